// Round 2
// baseline (5031.407 us; speedup 1.0000x reference)
//
#include <hip/hip_runtime.h>
#include <hip/hip_bf16.h>
#include <cstddef>

// All inputs/outputs are float32 (reference uses jax default fp32).

// bn: y = x*s + t, s = g*rsqrt(v+eps), t = b - m*s
__device__ __forceinline__ void bn_coef(const float* __restrict__ p, int C, int c,
                                        float& s, float& t) {
    float g = p[c];
    float b = p[C + c];
    float m = p[2 * C + c];
    float v = p[3 * C + c];
    s = g * rsqrtf(v + 1e-5f);
    t = b - m * s;
}

// ---------------- dilated 3x3 conv (d=2,p=2) + BN + ReLU, 96x96, co=64 ----------
// grid(8, 48, 2) block(96, 2); 8 co per thread (weight addrs wave-uniform).
template <int CI>
__global__ __launch_bounds__(192) void k_dconv(const float* __restrict__ in,
                                               const float* __restrict__ w,
                                               const float* __restrict__ bnp,
                                               float* __restrict__ out) {
    const int x = threadIdx.x;                  // 0..95
    const int y = blockIdx.y * 2 + threadIdx.y; // 0..95
    const int n = blockIdx.z;
    const int cg = blockIdx.x;                  // 8 groups of 8 co
    float acc[8];
#pragma unroll
    for (int j = 0; j < 8; ++j) acc[j] = 0.f;
    for (int ci = 0; ci < CI; ++ci) {
        const float* base = in + ((size_t)(n * CI + ci) * 96) * 96;
        const float* wci = w + ((size_t)(cg * 8) * CI + ci) * 9;
#pragma unroll
        for (int ky = 0; ky < 3; ++ky) {
            int yy = y + 2 * ky - 2;
            if (yy < 0 || yy > 95) continue;
            const float* row = base + yy * 96;
            float i0 = (x >= 2) ? row[x - 2] : 0.f;
            float i1 = row[x];
            float i2 = (x <= 93) ? row[x + 2] : 0.f;
#pragma unroll
            for (int j = 0; j < 8; ++j) {
                const float* wr = wci + (size_t)j * CI * 9 + ky * 3;
                acc[j] = fmaf(i0, wr[0], fmaf(i1, wr[1], fmaf(i2, wr[2], acc[j])));
            }
        }
    }
#pragma unroll
    for (int j = 0; j < 8; ++j) {
        int co = cg * 8 + j;
        float s, t; bn_coef(bnp, 64, co, s, t);
        out[(((size_t)n * 64 + co) * 96 + y) * 96 + x] = fmaxf(fmaf(acc[j], s, t), 0.f);
    }
}

// ---------------- 1x1 conv on c2 at 48x48 (512->64), raw (bn after resize) -----
// grid(8, 12, 2) block(48, 4)
__global__ __launch_bounds__(192) void k_conv1x1_c2(const float* __restrict__ c2,
                                                    const float* __restrict__ w,
                                                    float* __restrict__ out) {
    const int x = threadIdx.x;
    const int y = blockIdx.y * 4 + threadIdx.y;
    const int n = blockIdx.z;
    const int cg = blockIdx.x;
    const int p = y * 48 + x;
    float acc[8];
#pragma unroll
    for (int j = 0; j < 8; ++j) acc[j] = 0.f;
    for (int ci = 0; ci < 512; ++ci) {
        float iv = c2[(size_t)(n * 512 + ci) * 2304 + p];
#pragma unroll
        for (int j = 0; j < 8; ++j)
            acc[j] = fmaf(iv, w[(size_t)(cg * 8 + j) * 512 + ci], acc[j]);
    }
#pragma unroll
    for (int j = 0; j < 8; ++j)
        out[(size_t)(n * 64 + cg * 8 + j) * 2304 + p] = acc[j];
}

// ---------------- bilinear 48->96 (align_corners), optional BN+ReLU -------------
__global__ void k_up96(const float* __restrict__ src, float* __restrict__ dst,
                       int C, const float* __restrict__ bnp) {
    int idx = blockIdx.x * blockDim.x + threadIdx.x;  // 2*C*9216
    int p = idx % 9216;
    int nc = idx / 9216;
    int c = nc % C;
    int y = p / 96, x = p % 96;
    int yn = y * 47, xn = x * 47;
    int y0 = yn / 95, x0 = xn / 95;
    float wy = (float)(yn - y0 * 95) * (1.f / 95.f);
    float wx = (float)(xn - x0 * 95) * (1.f / 95.f);
    int y1 = min(y0 + 1, 47), x1 = min(x0 + 1, 47);
    const float* sp = src + (size_t)nc * 2304;
    float v00 = sp[y0 * 48 + x0], v01 = sp[y0 * 48 + x1];
    float v10 = sp[y1 * 48 + x0], v11 = sp[y1 * 48 + x1];
    float v = (v00 * (1.f - wx) + v01 * wx) * (1.f - wy)
            + (v10 * (1.f - wx) + v11 * wx) * wy;
    if (bnp) {
        float s, t; bn_coef(bnp, C, c, s, t);
        v = fmaxf(fmaf(v, s, t), 0.f);
    }
    dst[idx] = v;
}

// ---------------- energy + softmax -> att [n,9216,9] ---------------------------
__global__ __launch_bounds__(256) void k_attention(const float* __restrict__ q,
                                                   const float* __restrict__ kf,
                                                   float* __restrict__ att) {
    int tid = blockIdx.x * 256 + threadIdx.x;  // 2*9216
    int n = tid / 9216, p = tid % 9216;
    int y = p / 96, x = p % 96;
    float qv[64];
    const float* qb = q + (size_t)n * 64 * 9216 + p;
#pragma unroll
    for (int c = 0; c < 64; ++c) qv[c] = qb[(size_t)c * 9216];
    float e[9];
    const float* kb = kf + (size_t)n * 64 * 9216;
#pragma unroll
    for (int ky = 0; ky < 3; ++ky)
#pragma unroll
        for (int kx = 0; kx < 3; ++kx) {
            int yy = y + 2 * ky - 2, xx = x + 2 * kx - 2;
            float s = 0.f;
            if (yy >= 0 && yy < 96 && xx >= 0 && xx < 96) {
                const float* kp = kb + yy * 96 + xx;
#pragma unroll
                for (int c = 0; c < 64; ++c) s = fmaf(qv[c], kp[(size_t)c * 9216], s);
            }
            e[ky * 3 + kx] = s;
        }
    float m = e[0];
#pragma unroll
    for (int k = 1; k < 9; ++k) m = fmaxf(m, e[k]);
    float sum = 0.f;
#pragma unroll
    for (int k = 0; k < 9; ++k) { e[k] = __expf(e[k] - m); sum += e[k]; }
    float inv = 1.f / sum;
    float* ap = att + (size_t)tid * 9;
#pragma unroll
    for (int k = 0; k < 9; ++k) ap[k] = e[k] * inv;
}

// ---------------- adaptive avg pools s=1,2,3,6 -> pooled [n,2048,50] ------------
// grid(4096) block(64); thread t handles row y=t of one (n,c) plane.
__global__ __launch_bounds__(64) void k_pool(const float* __restrict__ xin,
                                             float* __restrict__ pooled) {
    int b = blockIdx.x;            // n*2048+c
    int t = threadIdx.x;
    __shared__ float cells[50];
    if (t < 50) cells[t] = 0.f;
    __syncthreads();
    float rs = 0.f;
    if (t < 48) {
        const float* row = xin + (size_t)b * 2304 + t * 48;
        float s6[6];
#pragma unroll
        for (int j = 0; j < 6; ++j) {
            float s = 0.f;
#pragma unroll
            for (int i = 0; i < 8; ++i) s += row[j * 8 + i];
            s6[j] = s;
        }
        float s3a = s6[0] + s6[1], s3b = s6[2] + s6[3], s3c = s6[4] + s6[5];
        float s2a = s3a + s6[2], s2b = s6[3] + s3c;
        rs = s2a + s2b;
        int r6 = t >> 3, r3 = t >> 4, r2 = t / 24;
        atomicAdd(&cells[14 + r6 * 6 + 0], s6[0]);
        atomicAdd(&cells[14 + r6 * 6 + 1], s6[1]);
        atomicAdd(&cells[14 + r6 * 6 + 2], s6[2]);
        atomicAdd(&cells[14 + r6 * 6 + 3], s6[3]);
        atomicAdd(&cells[14 + r6 * 6 + 4], s6[4]);
        atomicAdd(&cells[14 + r6 * 6 + 5], s6[5]);
        atomicAdd(&cells[5 + r3 * 3 + 0], s3a);
        atomicAdd(&cells[5 + r3 * 3 + 1], s3b);
        atomicAdd(&cells[5 + r3 * 3 + 2], s3c);
        atomicAdd(&cells[1 + r2 * 2 + 0], s2a);
        atomicAdd(&cells[1 + r2 * 2 + 1], s2b);
    }
#pragma unroll
    for (int off = 32; off > 0; off >>= 1) rs += __shfl_down(rs, off);
    if (t == 0) atomicAdd(&cells[0], rs);
    __syncthreads();
    if (t < 50) {
        float inv = (t == 0) ? (1.f / 2304.f)
                  : (t < 5)  ? (1.f / 576.f)
                  : (t < 14) ? (1.f / 256.f)
                             : (1.f / 64.f);
        pooled[(size_t)b * 50 + t] = cells[t] * inv;
    }
}

// ---------------- 1x1 conv 2048->512 per pooled cell + BN + ReLU ----------------
// grid(50, 2) block(512)
__global__ __launch_bounds__(512) void k_pconv(const float* __restrict__ pooled,
        const float* __restrict__ wp1, const float* __restrict__ bn1,
        const float* __restrict__ wp2, const float* __restrict__ bn2,
        const float* __restrict__ wp3, const float* __restrict__ bn3,
        const float* __restrict__ wp4, const float* __restrict__ bn4,
        float* __restrict__ pconv) {
    int cell = blockIdx.x, n = blockIdx.y, co = threadIdx.x;
    const float* w; const float* bnp;
    if (cell == 0)      { w = wp1; bnp = bn1; }
    else if (cell < 5)  { w = wp2; bnp = bn2; }
    else if (cell < 14) { w = wp3; bnp = bn3; }
    else                { w = wp4; bnp = bn4; }
    const float* pin = pooled + (size_t)n * 2048 * 50 + cell;
    float a = 0.f;
    for (int ci = 0; ci < 2048; ++ci)
        a = fmaf(pin[ci * 50], w[(size_t)co * 2048 + ci], a);
    float s, t; bn_coef(bnp, 512, co, s, t);
    pconv[((size_t)n * 512 + co) * 50 + cell] = fmaxf(fmaf(a, s, t), 0.f);
}

// ---------------- M[n,co,tap,cell] = sum_c W5[co, ch(b,c), tap] * pconv[n,c,cell]
// grid(9, 512, 2) block(64); lane = cell (0..49).
__global__ __launch_bounds__(64) void k_computeM(const float* __restrict__ w5,
                                                 const float* __restrict__ pconv,
                                                 float* __restrict__ M) {
    int tap = blockIdx.x, co = blockIdx.y, n = blockIdx.z;
    int cell = threadIdx.x;
    if (cell >= 50) return;
    int b = (cell == 0) ? 0 : (cell < 5) ? 1 : (cell < 14) ? 2 : 3;
    const float* wb = w5 + ((size_t)co * 4096 + 2048 + b * 512) * 9 + tap;
    const float* pc = pconv + (size_t)n * 512 * 50 + cell;
    float a = 0.f;
    for (int c = 0; c < 512; ++c)
        a = fmaf(wb[(size_t)c * 9], pc[(size_t)c * 50], a);
    M[(((size_t)n * 512 + co) * 9 + tap) * 50 + cell] = a;
}

// bilinear cell coefficients for branch with grid s x s at pixel (yy,xx) in 48x48
struct B4 { int c0, c1, c2, c3; float w0, w1, w2, w3; };
__device__ __forceinline__ B4 cell_interp(int yy, int xx, int s, int base) {
    int sm1 = s - 1;
    int yn = yy * sm1, xn = xx * sm1;
    int y0 = yn / 47, x0 = xn / 47;
    float wy = (float)(yn - y0 * 47) * (1.f / 47.f);
    float wx = (float)(xn - x0 * 47) * (1.f / 47.f);
    int y1 = min(y0 + 1, sm1), x1 = min(x0 + 1, sm1);
    B4 r;
    r.c0 = base + y0 * s + x0; r.c1 = base + y0 * s + x1;
    r.c2 = base + y1 * s + x0; r.c3 = base + y1 * s + x1;
    r.w0 = (1.f - wy) * (1.f - wx); r.w1 = (1.f - wy) * wx;
    r.w2 = wy * (1.f - wx);         r.w3 = wy * wx;
    return r;
}

// ---------------- conv5: 3x3 over [x(2048) ; psp-extra via M], + BN + ReLU ------
// grid(64, 12, 2) block(48, 4); 8 co per thread, weights wave-uniform.
__global__ __launch_bounds__(192) void k_conv5(const float* __restrict__ xin,
                                               const float* __restrict__ w,
                                               const float* __restrict__ M,
                                               const float* __restrict__ bnp,
                                               float* __restrict__ out) {
    const int x = threadIdx.x;                   // 0..47
    const int y = blockIdx.y * 4 + threadIdx.y;  // 0..47
    const int n = blockIdx.z;
    const int cg = blockIdx.x;                   // 64 groups of 8 co
    float acc[8];
#pragma unroll
    for (int j = 0; j < 8; ++j) acc[j] = 0.f;
    // part 1: direct conv over x's 2048 channels
    for (int ci = 0; ci < 2048; ++ci) {
        const float* src = xin + (size_t)(n * 2048 + ci) * 2304;
        const float* wci = w + ((size_t)(cg * 8) * 4096 + ci) * 9;
#pragma unroll
        for (int ky = 0; ky < 3; ++ky) {
            int yy = y + ky - 1;
            if (yy < 0 || yy > 47) continue;
            const float* row = src + yy * 48;
            float i0 = (x >= 1) ? row[x - 1] : 0.f;
            float i1 = row[x];
            float i2 = (x <= 46) ? row[x + 1] : 0.f;
#pragma unroll
            for (int j = 0; j < 8; ++j) {
                const float* wr = wci + (size_t)j * 4096 * 9 + ky * 3;
                acc[j] = fmaf(i0, wr[0], fmaf(i1, wr[1], fmaf(i2, wr[2], acc[j])));
            }
        }
    }
    // part 2: psp-extra channels via M (13 cell coefficients per tap)
    const float* Mbase = M + ((size_t)(n * 512 + cg * 8) * 9) * 50;
#pragma unroll
    for (int ky = 0; ky < 3; ++ky) {
        int yy = y + ky - 1;
        if (yy < 0 || yy > 47) continue;
#pragma unroll
        for (int kx = 0; kx < 3; ++kx) {
            int xx = x + kx - 1;
            if (xx < 0 || xx > 47) continue;
            int tap = ky * 3 + kx;
            B4 b2 = cell_interp(yy, xx, 2, 1);
            B4 b3 = cell_interp(yy, xx, 3, 5);
            B4 b6 = cell_interp(yy, xx, 6, 14);
#pragma unroll
            for (int j = 0; j < 8; ++j) {
                const float* Mp = Mbase + (size_t)j * 9 * 50 + tap * 50;
                float s = Mp[0];  // s=1 branch, weight 1
                s = fmaf(b2.w0, Mp[b2.c0], s); s = fmaf(b2.w1, Mp[b2.c1], s);
                s = fmaf(b2.w2, Mp[b2.c2], s); s = fmaf(b2.w3, Mp[b2.c3], s);
                s = fmaf(b3.w0, Mp[b3.c0], s); s = fmaf(b3.w1, Mp[b3.c1], s);
                s = fmaf(b3.w2, Mp[b3.c2], s); s = fmaf(b3.w3, Mp[b3.c3], s);
                s = fmaf(b6.w0, Mp[b6.c0], s); s = fmaf(b6.w1, Mp[b6.c1], s);
                s = fmaf(b6.w2, Mp[b6.c2], s); s = fmaf(b6.w3, Mp[b6.c3], s);
                acc[j] += s;
            }
        }
    }
    const int p = y * 48 + x;
#pragma unroll
    for (int j = 0; j < 8; ++j) {
        int co = cg * 8 + j;
        float s, t; bn_coef(bnp, 512, co, s, t);
        out[(size_t)(n * 512 + co) * 2304 + p] = fmaxf(fmaf(acc[j], s, t), 0.f);
    }
}

// ---------------- conv6 at 48x48 (512->59, no bias) -----------------------------
// grid(59, 12, 2) block(48, 4)
__global__ __launch_bounds__(192) void k_conv6s(const float* __restrict__ c5o,
                                                const float* __restrict__ w,
                                                float* __restrict__ out) {
    const int x = threadIdx.x;
    const int y = blockIdx.y * 4 + threadIdx.y;
    const int n = blockIdx.z;
    const int co = blockIdx.x;
    const int p = y * 48 + x;
    const float* ip = c5o + (size_t)n * 512 * 2304 + p;
    const float* wr = w + (size_t)co * 512;
    float a = 0.f;
    for (int ci = 0; ci < 512; ++ci)
        a = fmaf(ip[(size_t)ci * 2304], wr[ci], a);
    out[((size_t)n * 59 + co) * 2304 + p] = a;
}

// ---------------- final: out = bias + sum_k att[k]*c6o[tap_k] -------------------
__global__ void k_final(const float* __restrict__ att, const float* __restrict__ c6o,
                        const float* __restrict__ bias, float* __restrict__ out) {
    int idx = blockIdx.x * blockDim.x + threadIdx.x;  // 2*59*9216
    int p = idx % 9216;
    int nc = idx / 9216;
    int cls = nc % 59, n = nc / 59;
    int y = p / 96, x = p % 96;
    const float* ar = att + ((size_t)n * 9216 + p) * 9;
    const float* cp = c6o + (size_t)nc * 9216;
    float a = bias[cls];
#pragma unroll
    for (int ky = 0; ky < 3; ++ky)
#pragma unroll
        for (int kx = 0; kx < 3; ++kx) {
            int yy = y + 2 * ky - 2, xx = x + 2 * kx - 2;
            if (yy >= 0 && yy < 96 && xx >= 0 && xx < 96)
                a = fmaf(ar[ky * 3 + kx], cp[yy * 96 + xx], a);
        }
    out[idx] = a;
}

extern "C" void kernel_launch(void* const* d_in, const int* in_sizes, int n_in,
                              void* d_out, int out_size, void* d_ws, size_t ws_size,
                              hipStream_t stream) {
    const float* c1    = (const float*)d_in[0];
    const float* c2    = (const float*)d_in[1];
    const float* xin   = (const float*)d_in[2];
    const float* w_r1  = (const float*)d_in[3];
    const float* bn_r1 = (const float*)d_in[4];
    const float* w_r2  = (const float*)d_in[5];
    const float* bn_r2 = (const float*)d_in[6];
    const float* w_r3  = (const float*)d_in[7];
    const float* bn_r3 = (const float*)d_in[8];
    const float* w_p1  = (const float*)d_in[9];
    const float* bn_p1 = (const float*)d_in[10];
    const float* w_p2  = (const float*)d_in[11];
    const float* bn_p2 = (const float*)d_in[12];
    const float* w_p3  = (const float*)d_in[13];
    const float* bn_p3 = (const float*)d_in[14];
    const float* w_p4  = (const float*)d_in[15];
    const float* bn_p4 = (const float*)d_in[16];
    const float* w_c5  = (const float*)d_in[17];
    const float* bn_c5 = (const float*)d_in[18];
    const float* w_c6  = (const float*)d_in[19];
    const float* b_c6  = (const float*)d_in[20];
    float* out = (float*)d_out;
    (void)in_sizes; (void)n_in; (void)out_size; (void)ws_size;

    // Workspace layout (floats), two phases alias the same region A.
    float* wsf = (float*)d_ws;
    float* att = wsf;                         // 2*9216*9     = 165,888
    float* A   = wsf + 166144;                // aligned start of region A
    // phase 1 (attention branch):
    float* r1    = A;                         // 2*64*9216 = 1,179,648
    float* q     = r1 + 1179648;              // 1,179,648
    float* tmp64 = q + 1179648;               // 2*64*2304 =   294,912
    float* c2r   = tmp64 + 294912;            // 1,179,648  (A ends +3,833,856)
    // phase 2 (psp branch) — reuses region A:
    float* pooled = A;                        // 2*2048*50 =   204,800
    float* pconv  = pooled + 204800;          // 2*512*50  =    51,200
    float* M      = pconv + 51200;            // 2*512*9*50 =  460,800
    float* c5out  = M + 460800;               // 2*512*2304 = 2,359,296
    float* c6s    = c5out + 2359296;          // 2*59*2304 =   271,872
    float* c6o    = c6s + 271872;             // 2*59*9216 = 1,087,488 (ends +4,435,456)
    // total ws = (166,144 + 4,435,456) * 4 B ≈ 18.4 MB

    // ---- phase 1: attention branch ----
    k_dconv<256><<<dim3(8, 48, 2), dim3(96, 2), 0, stream>>>(c1, w_r1, bn_r1, r1);
    k_dconv<64><<<dim3(8, 48, 2), dim3(96, 2), 0, stream>>>(r1, w_r2, bn_r2, q);
    k_conv1x1_c2<<<dim3(8, 12, 2), dim3(48, 4), 0, stream>>>(c2, w_r3, tmp64);
    k_up96<<<dim3(2 * 64 * 9216 / 256), 256, 0, stream>>>(tmp64, c2r, 64, bn_r3);
    k_attention<<<dim3(2 * 9216 / 256), 256, 0, stream>>>(q, c2r, att);
    // ---- phase 2: psp branch ----
    k_pool<<<dim3(4096), 64, 0, stream>>>(xin, pooled);
    k_pconv<<<dim3(50, 2), 512, 0, stream>>>(pooled, w_p1, bn_p1, w_p2, bn_p2,
                                             w_p3, bn_p3, w_p4, bn_p4, pconv);
    k_computeM<<<dim3(9, 512, 2), 64, 0, stream>>>(w_c5, pconv, M);
    k_conv5<<<dim3(64, 12, 2), dim3(48, 4), 0, stream>>>(xin, w_c5, M, bn_c5, c5out);
    // classifier (conv6 commuted before upsample) + attention aggregation
    k_conv6s<<<dim3(59, 12, 2), dim3(48, 4), 0, stream>>>(c5out, w_c6, c6s);
    k_up96<<<dim3(2 * 59 * 9216 / 256), 256, 0, stream>>>(c6s, c6o, 59, nullptr);
    k_final<<<dim3(2 * 59 * 9216 / 256), 256, 0, stream>>>(att, c6o, b_c6, out);
}

// Round 3
// 1423.465 us; speedup vs baseline: 3.5346x; 3.5346x over previous
//
#include <hip/hip_runtime.h>
#include <hip/hip_bf16.h>
#include <cstddef>
#include <cstdint>

typedef __hip_bfloat16 hbf;
typedef __bf16 bf16x8 __attribute__((ext_vector_type(8)));
typedef float f32x4 __attribute__((ext_vector_type(4)));

// bn: y = x*s + t, s = g*rsqrt(v+eps), t = b - m*s
__device__ __forceinline__ void bn_coef(const float* __restrict__ p, int C, int c,
                                        float& s, float& t) {
    float g = p[c];
    float b = p[C + c];
    float m = p[2 * C + c];
    float v = p[3 * C + c];
    s = g * rsqrtf(v + 1e-5f);
    t = b - m * s;
}

// ---------------- dilated 3x3 conv (d=2,p=2) + BN + ReLU, 96x96, co=64 ----------
template <int CI>
__global__ __launch_bounds__(192) void k_dconv(const float* __restrict__ in,
                                               const float* __restrict__ w,
                                               const float* __restrict__ bnp,
                                               float* __restrict__ out) {
    const int x = threadIdx.x;                  // 0..95
    const int y = blockIdx.y * 2 + threadIdx.y; // 0..95
    const int n = blockIdx.z;
    const int cg = blockIdx.x;                  // 8 groups of 8 co
    float acc[8];
#pragma unroll
    for (int j = 0; j < 8; ++j) acc[j] = 0.f;
    for (int ci = 0; ci < CI; ++ci) {
        const float* base = in + ((size_t)(n * CI + ci) * 96) * 96;
        const float* wci = w + ((size_t)(cg * 8) * CI + ci) * 9;
#pragma unroll
        for (int ky = 0; ky < 3; ++ky) {
            int yy = y + 2 * ky - 2;
            if (yy < 0 || yy > 95) continue;
            const float* row = base + yy * 96;
            float i0 = (x >= 2) ? row[x - 2] : 0.f;
            float i1 = row[x];
            float i2 = (x <= 93) ? row[x + 2] : 0.f;
#pragma unroll
            for (int j = 0; j < 8; ++j) {
                const float* wr = wci + (size_t)j * CI * 9 + ky * 3;
                acc[j] = fmaf(i0, wr[0], fmaf(i1, wr[1], fmaf(i2, wr[2], acc[j])));
            }
        }
    }
#pragma unroll
    for (int j = 0; j < 8; ++j) {
        int co = cg * 8 + j;
        float s, t; bn_coef(bnp, 64, co, s, t);
        out[(((size_t)n * 64 + co) * 96 + y) * 96 + x] = fmaxf(fmaf(acc[j], s, t), 0.f);
    }
}

// ---------------- 1x1 conv on c2 at 48x48 (512->64) ----------------------------
__global__ __launch_bounds__(192) void k_conv1x1_c2(const float* __restrict__ c2,
                                                    const float* __restrict__ w,
                                                    float* __restrict__ out) {
    const int x = threadIdx.x;
    const int y = blockIdx.y * 4 + threadIdx.y;
    const int n = blockIdx.z;
    const int cg = blockIdx.x;
    const int p = y * 48 + x;
    float acc[8];
#pragma unroll
    for (int j = 0; j < 8; ++j) acc[j] = 0.f;
    for (int ci = 0; ci < 512; ++ci) {
        float iv = c2[(size_t)(n * 512 + ci) * 2304 + p];
#pragma unroll
        for (int j = 0; j < 8; ++j)
            acc[j] = fmaf(iv, w[(size_t)(cg * 8 + j) * 512 + ci], acc[j]);
    }
#pragma unroll
    for (int j = 0; j < 8; ++j)
        out[(size_t)(n * 64 + cg * 8 + j) * 2304 + p] = acc[j];
}

// ---------------- bilinear 48->96 (align_corners), optional BN+ReLU -------------
__global__ void k_up96(const float* __restrict__ src, float* __restrict__ dst,
                       int C, const float* __restrict__ bnp) {
    int idx = blockIdx.x * blockDim.x + threadIdx.x;  // 2*C*9216
    int p = idx % 9216;
    int nc = idx / 9216;
    int c = nc % C;
    int y = p / 96, x = p % 96;
    int yn = y * 47, xn = x * 47;
    int y0 = yn / 95, x0 = xn / 95;
    float wy = (float)(yn - y0 * 95) * (1.f / 95.f);
    float wx = (float)(xn - x0 * 95) * (1.f / 95.f);
    int y1 = min(y0 + 1, 47), x1 = min(x0 + 1, 47);
    const float* sp = src + (size_t)nc * 2304;
    float v00 = sp[y0 * 48 + x0], v01 = sp[y0 * 48 + x1];
    float v10 = sp[y1 * 48 + x0], v11 = sp[y1 * 48 + x1];
    float v = (v00 * (1.f - wx) + v01 * wx) * (1.f - wy)
            + (v10 * (1.f - wx) + v11 * wx) * wy;
    if (bnp) {
        float s, t; bn_coef(bnp, C, c, s, t);
        v = fmaxf(fmaf(v, s, t), 0.f);
    }
    dst[idx] = v;
}

// ---------------- energy + softmax -> att [n,9216,9] ---------------------------
__global__ __launch_bounds__(256) void k_attention(const float* __restrict__ q,
                                                   const float* __restrict__ kf,
                                                   float* __restrict__ att) {
    int tid = blockIdx.x * 256 + threadIdx.x;  // 2*9216
    int n = tid / 9216, p = tid % 9216;
    int y = p / 96, x = p % 96;
    float qv[64];
    const float* qb = q + (size_t)n * 64 * 9216 + p;
#pragma unroll
    for (int c = 0; c < 64; ++c) qv[c] = qb[(size_t)c * 9216];
    float e[9];
    const float* kb = kf + (size_t)n * 64 * 9216;
#pragma unroll
    for (int ky = 0; ky < 3; ++ky)
#pragma unroll
        for (int kx = 0; kx < 3; ++kx) {
            int yy = y + 2 * ky - 2, xx = x + 2 * kx - 2;
            float s = 0.f;
            if (yy >= 0 && yy < 96 && xx >= 0 && xx < 96) {
                const float* kp = kb + yy * 96 + xx;
#pragma unroll
                for (int c = 0; c < 64; ++c) s = fmaf(qv[c], kp[(size_t)c * 9216], s);
            }
            e[ky * 3 + kx] = s;
        }
    float m = e[0];
#pragma unroll
    for (int k = 1; k < 9; ++k) m = fmaxf(m, e[k]);
    float sum = 0.f;
#pragma unroll
    for (int k = 0; k < 9; ++k) { e[k] = __expf(e[k] - m); sum += e[k]; }
    float inv = 1.f / sum;
    float* ap = att + (size_t)tid * 9;
#pragma unroll
    for (int k = 0; k < 9; ++k) ap[k] = e[k] * inv;
}

// ---------------- adaptive avg pools s=1,2,3,6 -> pooled [n,2048,50] ------------
__global__ __launch_bounds__(64) void k_pool(const float* __restrict__ xin,
                                             float* __restrict__ pooled) {
    int b = blockIdx.x;            // n*2048+c
    int t = threadIdx.x;
    __shared__ float cells[50];
    if (t < 50) cells[t] = 0.f;
    __syncthreads();
    float rs = 0.f;
    if (t < 48) {
        const float* row = xin + (size_t)b * 2304 + t * 48;
        float s6[6];
#pragma unroll
        for (int j = 0; j < 6; ++j) {
            float s = 0.f;
#pragma unroll
            for (int i = 0; i < 8; ++i) s += row[j * 8 + i];
            s6[j] = s;
        }
        float s3a = s6[0] + s6[1], s3b = s6[2] + s6[3], s3c = s6[4] + s6[5];
        float s2a = s3a + s6[2], s2b = s6[3] + s3c;
        rs = s2a + s2b;
        int r6 = t >> 3, r3 = t >> 4, r2 = t / 24;
        atomicAdd(&cells[14 + r6 * 6 + 0], s6[0]);
        atomicAdd(&cells[14 + r6 * 6 + 1], s6[1]);
        atomicAdd(&cells[14 + r6 * 6 + 2], s6[2]);
        atomicAdd(&cells[14 + r6 * 6 + 3], s6[3]);
        atomicAdd(&cells[14 + r6 * 6 + 4], s6[4]);
        atomicAdd(&cells[14 + r6 * 6 + 5], s6[5]);
        atomicAdd(&cells[5 + r3 * 3 + 0], s3a);
        atomicAdd(&cells[5 + r3 * 3 + 1], s3b);
        atomicAdd(&cells[5 + r3 * 3 + 2], s3c);
        atomicAdd(&cells[1 + r2 * 2 + 0], s2a);
        atomicAdd(&cells[1 + r2 * 2 + 1], s2b);
    }
#pragma unroll
    for (int off = 32; off > 0; off >>= 1) rs += __shfl_down(rs, off);
    if (t == 0) atomicAdd(&cells[0], rs);
    __syncthreads();
    if (t < 50) {
        float inv = (t == 0) ? (1.f / 2304.f)
                  : (t < 5)  ? (1.f / 576.f)
                  : (t < 14) ? (1.f / 256.f)
                             : (1.f / 64.f);
        pooled[(size_t)b * 50 + t] = cells[t] * inv;
    }
}

// ---------------- 1x1 conv 2048->512 per pooled cell + BN + ReLU ----------------
__global__ __launch_bounds__(512) void k_pconv(const float* __restrict__ pooled,
        const float* __restrict__ wp1, const float* __restrict__ bn1,
        const float* __restrict__ wp2, const float* __restrict__ bn2,
        const float* __restrict__ wp3, const float* __restrict__ bn3,
        const float* __restrict__ wp4, const float* __restrict__ bn4,
        float* __restrict__ pconv) {
    int cell = blockIdx.x, n = blockIdx.y, co = threadIdx.x;
    const float* w; const float* bnp;
    if (cell == 0)      { w = wp1; bnp = bn1; }
    else if (cell < 5)  { w = wp2; bnp = bn2; }
    else if (cell < 14) { w = wp3; bnp = bn3; }
    else                { w = wp4; bnp = bn4; }
    const float* pin = pooled + (size_t)n * 2048 * 50 + cell;
    float a = 0.f;
    for (int ci = 0; ci < 2048; ++ci)
        a = fmaf(pin[ci * 50], w[(size_t)co * 2048 + ci], a);
    float s, t; bn_coef(bnp, 512, co, s, t);
    pconv[((size_t)n * 512 + co) * 50 + cell] = fmaxf(fmaf(a, s, t), 0.f);
}

// ---------------- M[n,co,tap,cell] = sum_c W5[co, ch(b,c), tap] * pconv[n,c,cell]
__global__ __launch_bounds__(64) void k_computeM(const float* __restrict__ w5,
                                                 const float* __restrict__ pconv,
                                                 float* __restrict__ M) {
    int tap = blockIdx.x, co = blockIdx.y, n = blockIdx.z;
    int cell = threadIdx.x;
    if (cell >= 50) return;
    int b = (cell == 0) ? 0 : (cell < 5) ? 1 : (cell < 14) ? 2 : 3;
    const float* wb = w5 + ((size_t)co * 4096 + 2048 + b * 512) * 9 + tap;
    const float* pc = pconv + (size_t)n * 512 * 50 + cell;
    float a = 0.f;
    for (int c = 0; c < 512; ++c)
        a = fmaf(wb[(size_t)c * 9], pc[(size_t)c * 50], a);
    M[(((size_t)n * 512 + co) * 9 + tap) * 50 + cell] = a;
}

// bilinear cell coefficients for branch with grid s x s at pixel (yy,xx) in 48x48
struct B4 { int c0, c1, c2, c3; float w0, w1, w2, w3; };
__device__ __forceinline__ B4 cell_interp(int yy, int xx, int s, int base) {
    int sm1 = s - 1;
    int yn = yy * sm1, xn = xx * sm1;
    int y0 = yn / 47, x0 = xn / 47;
    float wy = (float)(yn - y0 * 47) * (1.f / 47.f);
    float wx = (float)(xn - x0 * 47) * (1.f / 47.f);
    int y1 = min(y0 + 1, sm1), x1 = min(x0 + 1, sm1);
    B4 r;
    r.c0 = base + y0 * s + x0; r.c1 = base + y0 * s + x1;
    r.c2 = base + y1 * s + x0; r.c3 = base + y1 * s + x1;
    r.w0 = (1.f - wy) * (1.f - wx); r.w1 = (1.f - wy) * wx;
    r.w2 = wy * (1.f - wx);         r.w3 = wy * wx;
    return r;
}

// ---------------- zero-fill (dwords) --------------------------------------------
__global__ void k_fill0(uint32_t* __restrict__ p, int n) {
    int i = blockIdx.x * blockDim.x + threadIdx.x;
    if (i < n) p[i] = 0u;
}

// ---------------- x (fp32 [n,2048,48,48]) -> xtp (bf16 [n,50*50,2048], pad=0) ---
// grid(72, 64, 2) block(32, 8); LDS-tiled transpose.
__global__ __launch_bounds__(256) void k_xtrans(const float* __restrict__ x,
                                                hbf* __restrict__ xtp) {
    __shared__ float tbuf[32][33];
    const int p0 = blockIdx.x * 32, c0 = blockIdx.y * 32, n = blockIdx.z;
    const int tx = threadIdx.x, ty = threadIdx.y;
#pragma unroll
    for (int i = 0; i < 4; ++i) {
        int ci = c0 + ty * 4 + i;
        tbuf[ty * 4 + i][tx] = x[((size_t)(n * 2048 + ci)) * 2304 + p0 + tx];
    }
    __syncthreads();
#pragma unroll
    for (int i = 0; i < 4; ++i) {
        int p = p0 + ty * 4 + i;
        int pp = (p / 48 + 1) * 50 + (p % 48) + 1;
        xtp[((size_t)(n * 2500 + pp)) * 2048 + c0 + tx] = __float2bfloat16(tbuf[tx][ty * 4 + i]);
    }
}

// ---------------- w_c5 fp32 [co,4096,9] (ci<2048) -> wt bf16 [tap,co,ci] --------
__global__ __launch_bounds__(256) void k_wtrans(const float* __restrict__ w5,
                                                hbf* __restrict__ wt) {
    int idx = blockIdx.x * 256 + threadIdx.x;   // 512*2048
    int co = idx >> 11, ci = idx & 2047;
    const float* s = w5 + ((size_t)co * 4096 + ci) * 9;
#pragma unroll
    for (int tap = 0; tap < 9; ++tap)
        wt[((size_t)(tap * 512 + co)) * 2048 + ci] = __float2bfloat16(s[tap]);
}

// ---------------- conv5 direct part: MFMA implicit GEMM, split-K by tap group ---
// grid(4, 36, 3) block(256). Tile 128co x 128px, BK=32, taps g*3..g*3+2.
__global__ __launch_bounds__(256) void k_conv5_mfma(const hbf* __restrict__ wt,
                                                    const hbf* __restrict__ xtp,
                                                    float* __restrict__ c5acc) {
    __shared__ hbf As[4096];   // [128 m][32 k]
    __shared__ hbf Bs[4096];   // [128 n][32 k]
    const int tid = threadIdx.x;
    const int l = tid & 63, w = tid >> 6;
    const int m0 = blockIdx.x * 128;
    const int P0 = blockIdx.y * 128;
    const int g  = blockIdx.z;
    const int n_img = P0 / 2304;          // tile never straddles images (2304%128==0)
    const int pbase = P0 - n_img * 2304;
    const int r0 = tid >> 2;              // staging row 0..63
    const int koff = (tid & 3) * 8;       // element offset within row (16B chunks)

    const int p_r0 = pbase + r0;
    const int p_r1 = p_r0 + 64;
    const size_t bB0 = ((size_t)(n_img * 2500 + p_r0 + 2 * (p_r0 / 48) + 51)) * 2048 + koff;
    const size_t bB1 = ((size_t)(n_img * 2500 + p_r1 + 2 * (p_r1 / 48) + 51)) * 2048 + koff;

    const int wm = (w & 1) * 64, wn = (w >> 1) * 64;
    const int fragoff = (l & 15) * 32 + (l >> 4) * 8;
    f32x4 acc[4][4];
#pragma unroll
    for (int i = 0; i < 4; ++i)
#pragma unroll
        for (int j = 0; j < 4; ++j) acc[i][j] = {0.f, 0.f, 0.f, 0.f};

    hbf* ldsA0 = As + w * 512;            // wave-uniform bases (lane writes +l*16B)
    hbf* ldsA1 = As + 2048 + w * 512;
    hbf* ldsB0 = Bs + w * 512;
    hbf* ldsB1 = Bs + 2048 + w * 512;

    for (int t = 0; t < 3; ++t) {
        const int tap = g * 3 + t;
        const int dtap = (tap / 3 - 1) * 50 + (tap % 3 - 1);
        const hbf* gA0 = wt + ((size_t)(tap * 512 + m0 + r0)) * 2048 + koff;
        const hbf* gA1 = gA0 + (size_t)64 * 2048;
        const hbf* gB0 = xtp + bB0 + (ptrdiff_t)dtap * 2048;
        const hbf* gB1 = xtp + bB1 + (ptrdiff_t)dtap * 2048;
        for (int k0 = 0; k0 < 2048; k0 += 32) {
            __syncthreads();
            __builtin_amdgcn_global_load_lds(
                (const __attribute__((address_space(1))) void*)(gA0 + k0),
                (__attribute__((address_space(3))) void*)ldsA0, 16, 0, 0);
            __builtin_amdgcn_global_load_lds(
                (const __attribute__((address_space(1))) void*)(gA1 + k0),
                (__attribute__((address_space(3))) void*)ldsA1, 16, 0, 0);
            __builtin_amdgcn_global_load_lds(
                (const __attribute__((address_space(1))) void*)(gB0 + k0),
                (__attribute__((address_space(3))) void*)ldsB0, 16, 0, 0);
            __builtin_amdgcn_global_load_lds(
                (const __attribute__((address_space(1))) void*)(gB1 + k0),
                (__attribute__((address_space(3))) void*)ldsB1, 16, 0, 0);
            __syncthreads();
            bf16x8 af[4], bfr[4];
#pragma unroll
            for (int ti = 0; ti < 4; ++ti)
                af[ti] = *(const bf16x8*)(As + wm * 32 + ti * 512 + fragoff);
#pragma unroll
            for (int tj = 0; tj < 4; ++tj)
                bfr[tj] = *(const bf16x8*)(Bs + wn * 32 + tj * 512 + fragoff);
#pragma unroll
            for (int ti = 0; ti < 4; ++ti)
#pragma unroll
                for (int tj = 0; tj < 4; ++tj)
                    acc[ti][tj] = __builtin_amdgcn_mfma_f32_16x16x32_bf16(
                        af[ti], bfr[tj], acc[ti][tj], 0, 0, 0);
        }
    }
    // epilogue: D[m=quad*4+reg][n=lane&15] -> atomicAdd into c5acc
#pragma unroll
    for (int ti = 0; ti < 4; ++ti) {
        const int mrow = wm + ti * 16 + (l >> 4) * 4;
#pragma unroll
        for (int tj = 0; tj < 4; ++tj) {
            const int p = pbase + wn + tj * 16 + (l & 15);
            float* dst = c5acc + ((size_t)(n_img * 512 + m0 + mrow)) * 2304 + p;
#pragma unroll
            for (int r = 0; r < 4; ++r)
                atomicAdd(dst + (size_t)r * 2304, acc[ti][tj][r]);
        }
    }
}

// ---------------- epilogue: + psp(M)-part, BN, ReLU -> c5out bf16 ---------------
// grid(512, 2) block(256); 9 px per thread.
__global__ __launch_bounds__(256) void k_bnrelu_psp(const float* __restrict__ c5acc,
                                                    const float* __restrict__ M,
                                                    const float* __restrict__ bnp,
                                                    hbf* __restrict__ c5out) {
    const int co = blockIdx.x, n = blockIdx.y;
    __shared__ float Ms[450];
    const float* Mrow = M + ((size_t)(n * 512 + co)) * 450;
    for (int i = threadIdx.x; i < 450; i += 256) Ms[i] = Mrow[i];
    __syncthreads();
    float s, t; bn_coef(bnp, 512, co, s, t);
    const size_t base = ((size_t)(n * 512 + co)) * 2304;
#pragma unroll
    for (int i = 0; i < 9; ++i) {
        int p = threadIdx.x + i * 256;
        int y = p / 48, x = p % 48;
        float a = c5acc[base + p];
#pragma unroll
        for (int ky = 0; ky < 3; ++ky) {
            int yy = y + ky - 1;
            if (yy < 0 || yy > 47) continue;
#pragma unroll
            for (int kx = 0; kx < 3; ++kx) {
                int xx = x + kx - 1;
                if (xx < 0 || xx > 47) continue;
                const float* Mp = Ms + (ky * 3 + kx) * 50;
                float sa = Mp[0];
                B4 b2 = cell_interp(yy, xx, 2, 1);
                B4 b3 = cell_interp(yy, xx, 3, 5);
                B4 b6 = cell_interp(yy, xx, 6, 14);
                sa = fmaf(b2.w0, Mp[b2.c0], sa); sa = fmaf(b2.w1, Mp[b2.c1], sa);
                sa = fmaf(b2.w2, Mp[b2.c2], sa); sa = fmaf(b2.w3, Mp[b2.c3], sa);
                sa = fmaf(b3.w0, Mp[b3.c0], sa); sa = fmaf(b3.w1, Mp[b3.c1], sa);
                sa = fmaf(b3.w2, Mp[b3.c2], sa); sa = fmaf(b3.w3, Mp[b3.c3], sa);
                sa = fmaf(b6.w0, Mp[b6.c0], sa); sa = fmaf(b6.w1, Mp[b6.c1], sa);
                sa = fmaf(b6.w2, Mp[b6.c2], sa); sa = fmaf(b6.w3, Mp[b6.c3], sa);
                a += sa;
            }
        }
        c5out[base + p] = __float2bfloat16(fmaxf(fmaf(a, s, t), 0.f));
    }
}

// ---------------- conv6 at 48x48 (512->59, no bias), c5out bf16 -----------------
__global__ __launch_bounds__(192) void k_conv6s(const hbf* __restrict__ c5o,
                                                const float* __restrict__ w,
                                                float* __restrict__ out) {
    const int x = threadIdx.x;
    const int y = blockIdx.y * 4 + threadIdx.y;
    const int n = blockIdx.z;
    const int co = blockIdx.x;
    const int p = y * 48 + x;
    const hbf* ip = c5o + (size_t)n * 512 * 2304 + p;
    const float* wr = w + (size_t)co * 512;
    float a = 0.f;
    for (int ci = 0; ci < 512; ++ci)
        a = fmaf(__bfloat162float(ip[(size_t)ci * 2304]), wr[ci], a);
    out[((size_t)n * 59 + co) * 2304 + p] = a;
}

// ---------------- final: out = bias + sum_k att[k]*c6o[tap_k] -------------------
__global__ void k_final(const float* __restrict__ att, const float* __restrict__ c6o,
                        const float* __restrict__ bias, float* __restrict__ out) {
    int idx = blockIdx.x * blockDim.x + threadIdx.x;  // 2*59*9216
    int p = idx % 9216;
    int nc = idx / 9216;
    int cls = nc % 59, n = nc / 59;
    int y = p / 96, x = p % 96;
    const float* ar = att + ((size_t)n * 9216 + p) * 9;
    const float* cp = c6o + (size_t)nc * 9216;
    float a = bias[cls];
#pragma unroll
    for (int ky = 0; ky < 3; ++ky)
#pragma unroll
        for (int kx = 0; kx < 3; ++kx) {
            int yy = y + 2 * ky - 2, xx = x + 2 * kx - 2;
            if (yy >= 0 && yy < 96 && xx >= 0 && xx < 96)
                a = fmaf(ar[ky * 3 + kx], cp[yy * 96 + xx], a);
        }
    out[idx] = a;
}

extern "C" void kernel_launch(void* const* d_in, const int* in_sizes, int n_in,
                              void* d_out, int out_size, void* d_ws, size_t ws_size,
                              hipStream_t stream) {
    const float* c1    = (const float*)d_in[0];
    const float* c2    = (const float*)d_in[1];
    const float* xin   = (const float*)d_in[2];
    const float* w_r1  = (const float*)d_in[3];
    const float* bn_r1 = (const float*)d_in[4];
    const float* w_r2  = (const float*)d_in[5];
    const float* bn_r2 = (const float*)d_in[6];
    const float* w_r3  = (const float*)d_in[7];
    const float* bn_r3 = (const float*)d_in[8];
    const float* w_p1  = (const float*)d_in[9];
    const float* bn_p1 = (const float*)d_in[10];
    const float* w_p2  = (const float*)d_in[11];
    const float* bn_p2 = (const float*)d_in[12];
    const float* w_p3  = (const float*)d_in[13];
    const float* bn_p3 = (const float*)d_in[14];
    const float* w_p4  = (const float*)d_in[15];
    const float* bn_p4 = (const float*)d_in[16];
    const float* w_c5  = (const float*)d_in[17];
    const float* bn_c5 = (const float*)d_in[18];
    const float* w_c6  = (const float*)d_in[19];
    const float* b_c6  = (const float*)d_in[20];
    float* out = (float*)d_out;
    (void)in_sizes; (void)n_in; (void)out_size; (void)ws_size;

    // ---- workspace layout (bytes) ----
    char* base = (char*)d_ws;
    float* att = (float*)base;                    // 2*9216*9*4 = 663,552 B
    char*  A   = base + 663552;
    // phase 1 (attention branch), aliased region A:
    float* r1    = (float*)A;                     // 4,718,592 B
    float* q     = r1 + 1179648;                  // 4,718,592 B
    float* tmp64 = q + 1179648;                   // 1,179,648 B
    float* c2r   = tmp64 + 294912;                // 4,718,592 B
    // phase 2a (psp branch), aliased region A:
    hbf*   xtp    = (hbf*)A;                      // 2*2500*2048*2 = 20,480,000 B
    hbf*   wt     = (hbf*)(A + 20480000);         // 9*512*2048*2  = 18,874,368 B
    float* pooled = (float*)(A + 39354368);       //    819,200 B
    float* pconv  = (float*)(A + 40173568);       //    204,800 B
    float* M      = (float*)(A + 40378368);       //  1,843,200 B
    float* c5acc  = (float*)(A + 42221568);       //  9,437,184 B  (ends 51,658,752)
    // phase 2b (after conv5), aliased over xtp:
    hbf*   c5out = (hbf*)A;                       //  4,718,592 B
    float* c6s   = (float*)(A + 4718592);         //  1,087,488 B
    float* c6o   = (float*)(A + 5806080);         //  4,349,952 B  (ends 10,156,032 < xtp)
    // total ws required: 663,552 + 51,658,752 = 52,322,304 B (~49.9 MiB)

    // ---- phase 1: attention branch ----
    k_dconv<256><<<dim3(8, 48, 2), dim3(96, 2), 0, stream>>>(c1, w_r1, bn_r1, r1);
    k_dconv<64><<<dim3(8, 48, 2), dim3(96, 2), 0, stream>>>(r1, w_r2, bn_r2, q);
    k_conv1x1_c2<<<dim3(8, 12, 2), dim3(48, 4), 0, stream>>>(c2, w_r3, tmp64);
    k_up96<<<dim3(2 * 64 * 9216 / 256), 256, 0, stream>>>(tmp64, c2r, 64, bn_r3);
    k_attention<<<dim3(2 * 9216 / 256), 256, 0, stream>>>(q, c2r, att);
    // ---- phase 2: psp branch ----
    k_pool<<<dim3(4096), 64, 0, stream>>>(xin, pooled);
    k_pconv<<<dim3(50, 2), 512, 0, stream>>>(pooled, w_p1, bn_p1, w_p2, bn_p2,
                                             w_p3, bn_p3, w_p4, bn_p4, pconv);
    k_computeM<<<dim3(9, 512, 2), 64, 0, stream>>>(w_c5, pconv, M);
    k_fill0<<<dim3((5120000 + 255) / 256), 256, 0, stream>>>((uint32_t*)xtp, 5120000);
    k_xtrans<<<dim3(72, 64, 2), dim3(32, 8), 0, stream>>>(xin, xtp);
    k_wtrans<<<dim3(4096), 256, 0, stream>>>(w_c5, wt);
    k_fill0<<<dim3((2359296 + 255) / 256), 256, 0, stream>>>((uint32_t*)c5acc, 2359296);
    k_conv5_mfma<<<dim3(4, 36, 3), 256, 0, stream>>>(wt, xtp, c5acc);
    k_bnrelu_psp<<<dim3(512, 2), 256, 0, stream>>>(c5acc, M, bn_c5, c5out);
    // classifier (conv6 commuted before upsample) + attention aggregation
    k_conv6s<<<dim3(59, 12, 2), dim3(48, 4), 0, stream>>>(c5out, w_c6, c6s);
    k_up96<<<dim3(2 * 59 * 9216 / 256), 256, 0, stream>>>(c6s, c6o, 59, nullptr);
    k_final<<<dim3(2 * 59 * 9216 / 256), 256, 0, stream>>>(att, c6o, b_c6, out);
}

// Round 4
// 1006.910 us; speedup vs baseline: 4.9969x; 1.4137x over previous
//
#include <hip/hip_runtime.h>
#include <hip/hip_bf16.h>
#include <cstddef>
#include <cstdint>

typedef __hip_bfloat16 hbf;
typedef __bf16 bf16x8 __attribute__((ext_vector_type(8)));
typedef float f32x4 __attribute__((ext_vector_type(4)));

// bn: y = x*s + t, s = g*rsqrt(v+eps), t = b - m*s
__device__ __forceinline__ void bn_coef(const float* __restrict__ p, int C, int c,
                                        float& s, float& t) {
    float g = p[c];
    float b = p[C + c];
    float m = p[2 * C + c];
    float v = p[3 * C + c];
    s = g * rsqrtf(v + 1e-5f);
    t = b - m * s;
}

// ---------------- zero-fill (dwords) --------------------------------------------
__global__ void k_fill0(uint32_t* __restrict__ p, int n) {
    int i = blockIdx.x * blockDim.x + threadIdx.x;
    if (i < n) p[i] = 0u;
}

// ---------------- c1 fp32 [2,256,96,96] -> c1t bf16 [n][100*100][256], pad=2 ----
// grid(288, 8, 2) block(32, 8); LDS-tiled transpose (pad ring pre-zeroed).
__global__ __launch_bounds__(256) void k_c1trans(const float* __restrict__ x,
                                                 hbf* __restrict__ c1t) {
    __shared__ float tbuf[32][33];
    const int p0 = blockIdx.x * 32, c0 = blockIdx.y * 32, n = blockIdx.z;
    const int tx = threadIdx.x, ty = threadIdx.y;
#pragma unroll
    for (int i = 0; i < 4; ++i) {
        int ci = c0 + ty * 4 + i;
        tbuf[ty * 4 + i][tx] = x[((size_t)(n * 256 + ci)) * 9216 + p0 + tx];
    }
    __syncthreads();
#pragma unroll
    for (int i = 0; i < 4; ++i) {
        int p = p0 + ty * 4 + i;
        int pp = (p / 96 + 2) * 100 + (p % 96) + 2;
        c1t[((size_t)(n * 10000 + pp)) * 256 + c0 + tx] = __float2bfloat16(tbuf[tx][ty * 4 + i]);
    }
}

// ---------------- small conv weights [64,CI,3,3] fp32 -> [tap][64][CI] bf16 -----
template <int CI>
__global__ __launch_bounds__(256) void k_wtrans_small(const float* __restrict__ w,
                                                      hbf* __restrict__ wt) {
    int idx = blockIdx.x * 256 + threadIdx.x;   // 64*CI
    int co = idx / CI, ci = idx % CI;
    const float* s = w + ((size_t)(co * CI + ci)) * 9;
#pragma unroll
    for (int tap = 0; tap < 9; ++tap)
        wt[((size_t)(tap * 64 + co)) * CI + ci] = __float2bfloat16(s[tap]);
}

// ---------------- dilated 3x3 conv (d=2) MFMA: 64co x 64px tile, split-K by tap row
// grid(288, 3) block(256). it = padded-transposed input [n][100*100][CI].
template <int CI>
__global__ __launch_bounds__(256) void k_dconv_mfma(const hbf* __restrict__ wt,
                                                    const hbf* __restrict__ it,
                                                    float* __restrict__ accout) {
    __shared__ hbf As[2048];   // [64 m][32 k]
    __shared__ hbf Bs[2048];   // [64 n][32 k]
    const int tid = threadIdx.x;
    const int l = tid & 63, w = tid >> 6;
    const int P0 = blockIdx.x * 64;
    const int g  = blockIdx.y;
    const int r0 = tid >> 2;
    const int koff = (tid & 3) * 8;

    const int p_abs = P0 + r0;
    const int n_i = p_abs / 9216;
    const int pl = p_abs % 9216;
    const hbf* gB = it + ((size_t)(n_i * 10000 + (pl / 96 + 2) * 100 + (pl % 96) + 2)) * CI + koff;

    const int wn = w * 16;
    const int fragoff = (l & 15) * 32 + (l >> 4) * 8;
    f32x4 acc[4];
#pragma unroll
    for (int i = 0; i < 4; ++i) acc[i] = {0.f, 0.f, 0.f, 0.f};
    hbf* ldsA = As + w * 512;
    hbf* ldsB = Bs + w * 512;

    for (int t = 0; t < 3; ++t) {
        const int tap = g * 3 + t;
        const int dtap = (tap / 3 - 1) * 200 + (tap % 3 - 1) * 2;  // dilation-2 offsets
        const hbf* gA = wt + ((size_t)(tap * 64 + r0)) * CI + koff;
        const hbf* gBt = gB + (ptrdiff_t)dtap * CI;
        for (int k0 = 0; k0 < CI; k0 += 32) {
            __syncthreads();
            __builtin_amdgcn_global_load_lds(
                (const __attribute__((address_space(1))) void*)(gA + k0),
                (__attribute__((address_space(3))) void*)ldsA, 16, 0, 0);
            __builtin_amdgcn_global_load_lds(
                (const __attribute__((address_space(1))) void*)(gBt + k0),
                (__attribute__((address_space(3))) void*)ldsB, 16, 0, 0);
            __syncthreads();
            bf16x8 bfr = *(const bf16x8*)(Bs + wn * 32 + fragoff);
#pragma unroll
            for (int ti = 0; ti < 4; ++ti) {
                bf16x8 af = *(const bf16x8*)(As + ti * 512 + fragoff);
                acc[ti] = __builtin_amdgcn_mfma_f32_16x16x32_bf16(af, bfr, acc[ti], 0, 0, 0);
            }
        }
    }
    // epilogue: D row=co (quad*4+reg), col=px (lane&15) -> atomicAdd
    const int px = P0 + wn + (l & 15);
    const int n2 = px / 9216, pl2 = px % 9216;
#pragma unroll
    for (int ti = 0; ti < 4; ++ti) {
        const int mrow = ti * 16 + (l >> 4) * 4;
        float* dst = accout + ((size_t)(n2 * 64 + mrow)) * 9216 + pl2;
#pragma unroll
        for (int r = 0; r < 4; ++r)
            atomicAdd(dst + (size_t)r * 9216, acc[ti][r]);
    }
}

// ---------------- ep_r1: BN+ReLU(r1acc) -> r1t bf16 padded-transposed -----------
// grid(72) block(256); one px per thread, 64 co contiguous stores.
__global__ __launch_bounds__(256) void k_ep_r1(const float* __restrict__ acc,
                                               const float* __restrict__ bnp,
                                               hbf* __restrict__ r1t) {
    __shared__ float ss[64], st[64];
    if (threadIdx.x < 64) {
        float s, t; bn_coef(bnp, 64, threadIdx.x, s, t);
        ss[threadIdx.x] = s; st[threadIdx.x] = t;
    }
    __syncthreads();
    const int pi = blockIdx.x * 256 + threadIdx.x;
    const int n = pi / 9216, pl = pi % 9216;
    const int pp = (pl / 96 + 2) * 100 + (pl % 96) + 2;
    hbf* dst = r1t + ((size_t)(n * 10000 + pp)) * 64;
    const float* src = acc + (size_t)n * 64 * 9216 + pl;
#pragma unroll
    for (int co = 0; co < 64; ++co)
        dst[co] = __float2bfloat16(fmaxf(fmaf(src[(size_t)co * 9216], ss[co], st[co]), 0.f));
}

// ---------------- ep_q: elementwise BN+ReLU(qacc) -> q fp32 planar --------------
__global__ void k_ep_q(const float* __restrict__ acc, const float* __restrict__ bnp,
                       float* __restrict__ q) {
    int idx = blockIdx.x * blockDim.x + threadIdx.x;  // 2*64*9216
    int c = (idx / 9216) & 63;
    float s, t; bn_coef(bnp, 64, c, s, t);
    q[idx] = fmaxf(fmaf(acc[idx], s, t), 0.f);
}

// ---------------- 1x1 conv on c2 (512->64), ci split 4-ways, atomic -------------
// grid(16, 12, 8) block(48, 4): cg=4 co, bz = n*4 + ci-quarter.
__global__ __launch_bounds__(192) void k_conv1x1_c2(const float* __restrict__ c2,
                                                    const float* __restrict__ w,
                                                    float* __restrict__ outacc) {
    const int x = threadIdx.x;
    const int y = blockIdx.y * 4 + threadIdx.y;
    const int n = blockIdx.z >> 2;
    const int ci0 = (blockIdx.z & 3) * 128;
    const int cg = blockIdx.x;
    const int p = y * 48 + x;
    float acc[4];
#pragma unroll
    for (int j = 0; j < 4; ++j) acc[j] = 0.f;
    for (int ci = ci0; ci < ci0 + 128; ++ci) {
        float iv = c2[(size_t)(n * 512 + ci) * 2304 + p];
#pragma unroll
        for (int j = 0; j < 4; ++j)
            acc[j] = fmaf(iv, w[(size_t)(cg * 4 + j) * 512 + ci], acc[j]);
    }
#pragma unroll
    for (int j = 0; j < 4; ++j)
        atomicAdd(&outacc[(size_t)(n * 64 + cg * 4 + j) * 2304 + p], acc[j]);
}

// ---------------- bilinear 48->96 (align_corners), optional BN+ReLU -------------
__global__ void k_up96(const float* __restrict__ src, float* __restrict__ dst,
                       int C, const float* __restrict__ bnp) {
    int idx = blockIdx.x * blockDim.x + threadIdx.x;  // 2*C*9216
    int p = idx % 9216;
    int nc = idx / 9216;
    int c = nc % C;
    int y = p / 96, x = p % 96;
    int yn = y * 47, xn = x * 47;
    int y0 = yn / 95, x0 = xn / 95;
    float wy = (float)(yn - y0 * 95) * (1.f / 95.f);
    float wx = (float)(xn - x0 * 95) * (1.f / 95.f);
    int y1 = min(y0 + 1, 47), x1 = min(x0 + 1, 47);
    const float* sp = src + (size_t)nc * 2304;
    float v00 = sp[y0 * 48 + x0], v01 = sp[y0 * 48 + x1];
    float v10 = sp[y1 * 48 + x0], v11 = sp[y1 * 48 + x1];
    float v = (v00 * (1.f - wx) + v01 * wx) * (1.f - wy)
            + (v10 * (1.f - wx) + v11 * wx) * wy;
    if (bnp) {
        float s, t; bn_coef(bnp, C, c, s, t);
        v = fmaxf(fmaf(v, s, t), 0.f);
    }
    dst[idx] = v;
}

// ---------------- energy + softmax -> att [n,9216,9] ---------------------------
__global__ __launch_bounds__(256) void k_attention(const float* __restrict__ q,
                                                   const float* __restrict__ kf,
                                                   float* __restrict__ att) {
    int tid = blockIdx.x * 256 + threadIdx.x;  // 2*9216
    int n = tid / 9216, p = tid % 9216;
    int y = p / 96, x = p % 96;
    float qv[64];
    const float* qb = q + (size_t)n * 64 * 9216 + p;
#pragma unroll
    for (int c = 0; c < 64; ++c) qv[c] = qb[(size_t)c * 9216];
    float e[9];
    const float* kb = kf + (size_t)n * 64 * 9216;
#pragma unroll
    for (int ky = 0; ky < 3; ++ky)
#pragma unroll
        for (int kx = 0; kx < 3; ++kx) {
            int yy = y + 2 * ky - 2, xx = x + 2 * kx - 2;
            float s = 0.f;
            if (yy >= 0 && yy < 96 && xx >= 0 && xx < 96) {
                const float* kp = kb + yy * 96 + xx;
#pragma unroll
                for (int c = 0; c < 64; ++c) s = fmaf(qv[c], kp[(size_t)c * 9216], s);
            }
            e[ky * 3 + kx] = s;
        }
    float m = e[0];
#pragma unroll
    for (int k = 1; k < 9; ++k) m = fmaxf(m, e[k]);
    float sum = 0.f;
#pragma unroll
    for (int k = 0; k < 9; ++k) { e[k] = __expf(e[k] - m); sum += e[k]; }
    float inv = 1.f / sum;
    float* ap = att + (size_t)tid * 9;
#pragma unroll
    for (int k = 0; k < 9; ++k) ap[k] = e[k] * inv;
}

// ---------------- adaptive avg pools s=1,2,3,6 -> pooled [n,2048,50] ------------
__global__ __launch_bounds__(64) void k_pool(const float* __restrict__ xin,
                                             float* __restrict__ pooled) {
    int b = blockIdx.x;            // n*2048+c
    int t = threadIdx.x;
    __shared__ float cells[50];
    if (t < 50) cells[t] = 0.f;
    __syncthreads();
    float rs = 0.f;
    if (t < 48) {
        const float* row = xin + (size_t)b * 2304 + t * 48;
        float s6[6];
#pragma unroll
        for (int j = 0; j < 6; ++j) {
            float s = 0.f;
#pragma unroll
            for (int i = 0; i < 8; ++i) s += row[j * 8 + i];
            s6[j] = s;
        }
        float s3a = s6[0] + s6[1], s3b = s6[2] + s6[3], s3c = s6[4] + s6[5];
        float s2a = s3a + s6[2], s2b = s6[3] + s3c;
        rs = s2a + s2b;
        int r6 = t >> 3, r3 = t >> 4, r2 = t / 24;
        atomicAdd(&cells[14 + r6 * 6 + 0], s6[0]);
        atomicAdd(&cells[14 + r6 * 6 + 1], s6[1]);
        atomicAdd(&cells[14 + r6 * 6 + 2], s6[2]);
        atomicAdd(&cells[14 + r6 * 6 + 3], s6[3]);
        atomicAdd(&cells[14 + r6 * 6 + 4], s6[4]);
        atomicAdd(&cells[14 + r6 * 6 + 5], s6[5]);
        atomicAdd(&cells[5 + r3 * 3 + 0], s3a);
        atomicAdd(&cells[5 + r3 * 3 + 1], s3b);
        atomicAdd(&cells[5 + r3 * 3 + 2], s3c);
        atomicAdd(&cells[1 + r2 * 2 + 0], s2a);
        atomicAdd(&cells[1 + r2 * 2 + 1], s2b);
    }
#pragma unroll
    for (int off = 32; off > 0; off >>= 1) rs += __shfl_down(rs, off);
    if (t == 0) atomicAdd(&cells[0], rs);
    __syncthreads();
    if (t < 50) {
        float inv = (t == 0) ? (1.f / 2304.f)
                  : (t < 5)  ? (1.f / 576.f)
                  : (t < 14) ? (1.f / 256.f)
                             : (1.f / 64.f);
        pooled[(size_t)b * 50 + t] = cells[t] * inv;
    }
}

// ---------------- 1x1 conv 2048->512 per pooled cell + BN + ReLU ----------------
__global__ __launch_bounds__(512) void k_pconv(const float* __restrict__ pooled,
        const float* __restrict__ wp1, const float* __restrict__ bn1,
        const float* __restrict__ wp2, const float* __restrict__ bn2,
        const float* __restrict__ wp3, const float* __restrict__ bn3,
        const float* __restrict__ wp4, const float* __restrict__ bn4,
        float* __restrict__ pconv) {
    int cell = blockIdx.x, n = blockIdx.y, co = threadIdx.x;
    const float* w; const float* bnp;
    if (cell == 0)      { w = wp1; bnp = bn1; }
    else if (cell < 5)  { w = wp2; bnp = bn2; }
    else if (cell < 14) { w = wp3; bnp = bn3; }
    else                { w = wp4; bnp = bn4; }
    const float* pin = pooled + (size_t)n * 2048 * 50 + cell;
    float a = 0.f;
    for (int ci = 0; ci < 2048; ++ci)
        a = fmaf(pin[ci * 50], w[(size_t)co * 2048 + ci], a);
    float s, t; bn_coef(bnp, 512, co, s, t);
    pconv[((size_t)n * 512 + co) * 50 + cell] = fmaxf(fmaf(a, s, t), 0.f);
}

// ---------------- M[n,co,tap,cell] = sum_c W5[co, ch(b,c), tap] * pconv[n,c,cell]
__global__ __launch_bounds__(64) void k_computeM(const float* __restrict__ w5,
                                                 const float* __restrict__ pconv,
                                                 float* __restrict__ M) {
    int tap = blockIdx.x, co = blockIdx.y, n = blockIdx.z;
    int cell = threadIdx.x;
    if (cell >= 50) return;
    int b = (cell == 0) ? 0 : (cell < 5) ? 1 : (cell < 14) ? 2 : 3;
    const float* wb = w5 + ((size_t)co * 4096 + 2048 + b * 512) * 9 + tap;
    const float* pc = pconv + (size_t)n * 512 * 50 + cell;
    float a = 0.f;
    for (int c = 0; c < 512; ++c)
        a = fmaf(wb[(size_t)c * 9], pc[(size_t)c * 50], a);
    M[(((size_t)n * 512 + co) * 9 + tap) * 50 + cell] = a;
}

// bilinear cell coefficients for branch with grid s x s at pixel (yy,xx) in 48x48
struct B4 { int c0, c1, c2, c3; float w0, w1, w2, w3; };
__device__ __forceinline__ B4 cell_interp(int yy, int xx, int s, int base) {
    int sm1 = s - 1;
    int yn = yy * sm1, xn = xx * sm1;
    int y0 = yn / 47, x0 = xn / 47;
    float wy = (float)(yn - y0 * 47) * (1.f / 47.f);
    float wx = (float)(xn - x0 * 47) * (1.f / 47.f);
    int y1 = min(y0 + 1, sm1), x1 = min(x0 + 1, sm1);
    B4 r;
    r.c0 = base + y0 * s + x0; r.c1 = base + y0 * s + x1;
    r.c2 = base + y1 * s + x0; r.c3 = base + y1 * s + x1;
    r.w0 = (1.f - wy) * (1.f - wx); r.w1 = (1.f - wy) * wx;
    r.w2 = wy * (1.f - wx);         r.w3 = wy * wx;
    return r;
}

// ---------------- x (fp32 [n,2048,48,48]) -> xtp (bf16 [n,50*50,2048], pad=0) ---
__global__ __launch_bounds__(256) void k_xtrans(const float* __restrict__ x,
                                                hbf* __restrict__ xtp) {
    __shared__ float tbuf[32][33];
    const int p0 = blockIdx.x * 32, c0 = blockIdx.y * 32, n = blockIdx.z;
    const int tx = threadIdx.x, ty = threadIdx.y;
#pragma unroll
    for (int i = 0; i < 4; ++i) {
        int ci = c0 + ty * 4 + i;
        tbuf[ty * 4 + i][tx] = x[((size_t)(n * 2048 + ci)) * 2304 + p0 + tx];
    }
    __syncthreads();
#pragma unroll
    for (int i = 0; i < 4; ++i) {
        int p = p0 + ty * 4 + i;
        int pp = (p / 48 + 1) * 50 + (p % 48) + 1;
        xtp[((size_t)(n * 2500 + pp)) * 2048 + c0 + tx] = __float2bfloat16(tbuf[tx][ty * 4 + i]);
    }
}

// ---------------- w_c5 fp32 [co,4096,9] (ci<2048) -> wt bf16 [tap,co,ci] --------
__global__ __launch_bounds__(256) void k_wtrans(const float* __restrict__ w5,
                                                hbf* __restrict__ wt) {
    int idx = blockIdx.x * 256 + threadIdx.x;   // 512*2048
    int co = idx >> 11, ci = idx & 2047;
    const float* s = w5 + ((size_t)co * 4096 + ci) * 9;
#pragma unroll
    for (int tap = 0; tap < 9; ++tap)
        wt[((size_t)(tap * 512 + co)) * 2048 + ci] = __float2bfloat16(s[tap]);
}

// ---------------- conv5 direct part: MFMA implicit GEMM, split-K by tap group ---
// grid(4, 36, 3) block(256). Tile 128co x 128px, BK=32, taps g*3..g*3+2.
__global__ __launch_bounds__(256) void k_conv5_mfma(const hbf* __restrict__ wt,
                                                    const hbf* __restrict__ xtp,
                                                    float* __restrict__ c5acc) {
    __shared__ hbf As[4096];   // [128 m][32 k]
    __shared__ hbf Bs[4096];   // [128 n][32 k]
    const int tid = threadIdx.x;
    const int l = tid & 63, w = tid >> 6;
    const int m0 = blockIdx.x * 128;
    const int P0 = blockIdx.y * 128;
    const int g  = blockIdx.z;
    const int n_img = P0 / 2304;          // tile never straddles images (2304%128==0)
    const int pbase = P0 - n_img * 2304;
    const int r0 = tid >> 2;              // staging row 0..63
    const int koff = (tid & 3) * 8;       // element offset within row (16B chunks)

    const int p_r0 = pbase + r0;
    const int p_r1 = p_r0 + 64;
    const size_t bB0 = ((size_t)(n_img * 2500 + p_r0 + 2 * (p_r0 / 48) + 51)) * 2048 + koff;
    const size_t bB1 = ((size_t)(n_img * 2500 + p_r1 + 2 * (p_r1 / 48) + 51)) * 2048 + koff;

    const int wm = (w & 1) * 64, wn = (w >> 1) * 64;
    const int fragoff = (l & 15) * 32 + (l >> 4) * 8;
    f32x4 acc[4][4];
#pragma unroll
    for (int i = 0; i < 4; ++i)
#pragma unroll
        for (int j = 0; j < 4; ++j) acc[i][j] = {0.f, 0.f, 0.f, 0.f};

    hbf* ldsA0 = As + w * 512;            // wave-uniform bases (lane writes +l*16B)
    hbf* ldsA1 = As + 2048 + w * 512;
    hbf* ldsB0 = Bs + w * 512;
    hbf* ldsB1 = Bs + 2048 + w * 512;

    for (int t = 0; t < 3; ++t) {
        const int tap = g * 3 + t;
        const int dtap = (tap / 3 - 1) * 50 + (tap % 3 - 1);
        const hbf* gA0 = wt + ((size_t)(tap * 512 + m0 + r0)) * 2048 + koff;
        const hbf* gA1 = gA0 + (size_t)64 * 2048;
        const hbf* gB0 = xtp + bB0 + (ptrdiff_t)dtap * 2048;
        const hbf* gB1 = xtp + bB1 + (ptrdiff_t)dtap * 2048;
        for (int k0 = 0; k0 < 2048; k0 += 32) {
            __syncthreads();
            __builtin_amdgcn_global_load_lds(
                (const __attribute__((address_space(1))) void*)(gA0 + k0),
                (__attribute__((address_space(3))) void*)ldsA0, 16, 0, 0);
            __builtin_amdgcn_global_load_lds(
                (const __attribute__((address_space(1))) void*)(gA1 + k0),
                (__attribute__((address_space(3))) void*)ldsA1, 16, 0, 0);
            __builtin_amdgcn_global_load_lds(
                (const __attribute__((address_space(1))) void*)(gB0 + k0),
                (__attribute__((address_space(3))) void*)ldsB0, 16, 0, 0);
            __builtin_amdgcn_global_load_lds(
                (const __attribute__((address_space(1))) void*)(gB1 + k0),
                (__attribute__((address_space(3))) void*)ldsB1, 16, 0, 0);
            __syncthreads();
            bf16x8 af[4], bfr[4];
#pragma unroll
            for (int ti = 0; ti < 4; ++ti)
                af[ti] = *(const bf16x8*)(As + wm * 32 + ti * 512 + fragoff);
#pragma unroll
            for (int tj = 0; tj < 4; ++tj)
                bfr[tj] = *(const bf16x8*)(Bs + wn * 32 + tj * 512 + fragoff);
#pragma unroll
            for (int ti = 0; ti < 4; ++ti)
#pragma unroll
                for (int tj = 0; tj < 4; ++tj)
                    acc[ti][tj] = __builtin_amdgcn_mfma_f32_16x16x32_bf16(
                        af[ti], bfr[tj], acc[ti][tj], 0, 0, 0);
        }
    }
#pragma unroll
    for (int ti = 0; ti < 4; ++ti) {
        const int mrow = wm + ti * 16 + (l >> 4) * 4;
#pragma unroll
        for (int tj = 0; tj < 4; ++tj) {
            const int p = pbase + wn + tj * 16 + (l & 15);
            float* dst = c5acc + ((size_t)(n_img * 512 + m0 + mrow)) * 2304 + p;
#pragma unroll
            for (int r = 0; r < 4; ++r)
                atomicAdd(dst + (size_t)r * 2304, acc[ti][tj][r]);
        }
    }
}

// ---------------- epilogue: + psp(M)-part, BN, ReLU -> c5out bf16 ---------------
__global__ __launch_bounds__(256) void k_bnrelu_psp(const float* __restrict__ c5acc,
                                                    const float* __restrict__ M,
                                                    const float* __restrict__ bnp,
                                                    hbf* __restrict__ c5out) {
    const int co = blockIdx.x, n = blockIdx.y;
    __shared__ float Ms[450];
    const float* Mrow = M + ((size_t)(n * 512 + co)) * 450;
    for (int i = threadIdx.x; i < 450; i += 256) Ms[i] = Mrow[i];
    __syncthreads();
    float s, t; bn_coef(bnp, 512, co, s, t);
    const size_t base = ((size_t)(n * 512 + co)) * 2304;
#pragma unroll
    for (int i = 0; i < 9; ++i) {
        int p = threadIdx.x + i * 256;
        int y = p / 48, x = p % 48;
        float a = c5acc[base + p];
#pragma unroll
        for (int ky = 0; ky < 3; ++ky) {
            int yy = y + ky - 1;
            if (yy < 0 || yy > 47) continue;
#pragma unroll
            for (int kx = 0; kx < 3; ++kx) {
                int xx = x + kx - 1;
                if (xx < 0 || xx > 47) continue;
                const float* Mp = Ms + (ky * 3 + kx) * 50;
                float sa = Mp[0];
                B4 b2 = cell_interp(yy, xx, 2, 1);
                B4 b3 = cell_interp(yy, xx, 3, 5);
                B4 b6 = cell_interp(yy, xx, 6, 14);
                sa = fmaf(b2.w0, Mp[b2.c0], sa); sa = fmaf(b2.w1, Mp[b2.c1], sa);
                sa = fmaf(b2.w2, Mp[b2.c2], sa); sa = fmaf(b2.w3, Mp[b2.c3], sa);
                sa = fmaf(b3.w0, Mp[b3.c0], sa); sa = fmaf(b3.w1, Mp[b3.c1], sa);
                sa = fmaf(b3.w2, Mp[b3.c2], sa); sa = fmaf(b3.w3, Mp[b3.c3], sa);
                sa = fmaf(b6.w0, Mp[b6.c0], sa); sa = fmaf(b6.w1, Mp[b6.c1], sa);
                sa = fmaf(b6.w2, Mp[b6.c2], sa); sa = fmaf(b6.w3, Mp[b6.c3], sa);
                a += sa;
            }
        }
        c5out[base + p] = __float2bfloat16(fmaxf(fmaf(a, s, t), 0.f));
    }
}

// ---------------- conv6 at 48x48 (512->59, no bias), c5out bf16 -----------------
__global__ __launch_bounds__(192) void k_conv6s(const hbf* __restrict__ c5o,
                                                const float* __restrict__ w,
                                                float* __restrict__ out) {
    const int x = threadIdx.x;
    const int y = blockIdx.y * 4 + threadIdx.y;
    const int n = blockIdx.z;
    const int co = blockIdx.x;
    const int p = y * 48 + x;
    const hbf* ip = c5o + (size_t)n * 512 * 2304 + p;
    const float* wr = w + (size_t)co * 512;
    float a = 0.f;
    for (int ci = 0; ci < 512; ++ci)
        a = fmaf(__bfloat162float(ip[(size_t)ci * 2304]), wr[ci], a);
    out[((size_t)n * 59 + co) * 2304 + p] = a;
}

// ---------------- final: out = bias + sum_k att[k]*c6o[tap_k] -------------------
__global__ void k_final(const float* __restrict__ att, const float* __restrict__ c6o,
                        const float* __restrict__ bias, float* __restrict__ out) {
    int idx = blockIdx.x * blockDim.x + threadIdx.x;  // 2*59*9216
    int p = idx % 9216;
    int nc = idx / 9216;
    int cls = nc % 59, n = nc / 59;
    int y = p / 96, x = p % 96;
    const float* ar = att + ((size_t)n * 9216 + p) * 9;
    const float* cp = c6o + (size_t)nc * 9216;
    float a = bias[cls];
#pragma unroll
    for (int ky = 0; ky < 3; ++ky)
#pragma unroll
        for (int kx = 0; kx < 3; ++kx) {
            int yy = y + 2 * ky - 2, xx = x + 2 * kx - 2;
            if (yy >= 0 && yy < 96 && xx >= 0 && xx < 96)
                a = fmaf(ar[ky * 3 + kx], cp[yy * 96 + xx], a);
        }
    out[idx] = a;
}

extern "C" void kernel_launch(void* const* d_in, const int* in_sizes, int n_in,
                              void* d_out, int out_size, void* d_ws, size_t ws_size,
                              hipStream_t stream) {
    const float* c1    = (const float*)d_in[0];
    const float* c2    = (const float*)d_in[1];
    const float* xin   = (const float*)d_in[2];
    const float* w_r1  = (const float*)d_in[3];
    const float* bn_r1 = (const float*)d_in[4];
    const float* w_r2  = (const float*)d_in[5];
    const float* bn_r2 = (const float*)d_in[6];
    const float* w_r3  = (const float*)d_in[7];
    const float* bn_r3 = (const float*)d_in[8];
    const float* w_p1  = (const float*)d_in[9];
    const float* bn_p1 = (const float*)d_in[10];
    const float* w_p2  = (const float*)d_in[11];
    const float* bn_p2 = (const float*)d_in[12];
    const float* w_p3  = (const float*)d_in[13];
    const float* bn_p3 = (const float*)d_in[14];
    const float* w_p4  = (const float*)d_in[15];
    const float* bn_p4 = (const float*)d_in[16];
    const float* w_c5  = (const float*)d_in[17];
    const float* bn_c5 = (const float*)d_in[18];
    const float* w_c6  = (const float*)d_in[19];
    const float* b_c6  = (const float*)d_in[20];
    float* out = (float*)d_out;
    (void)in_sizes; (void)n_in; (void)out_size; (void)ws_size;

    char* base = (char*)d_ws;
    float* att = (float*)base;                    // 663,552 B
    char*  A   = base + 663552;
    // ---- phase 1 layout (region A) ----
    hbf*   c1t   = (hbf*)A;                       // 2*10000*256*2 = 10,240,000
    hbf*   r1t   = (hbf*)(A + 10240000);          // 2*10000*64*2  =  2,560,000
    float* r1acc = (float*)(A + 12800000);        // 2*64*9216*4   =  4,718,592
    float* qacc  = (float*)(A + 17518592);        // 4,718,592
    float* c2acc = (float*)(A + 22237184);        // 2*64*2304*4   =  1,179,648  (fill ends 23,416,832)
    float* q     = (float*)(A + 23416832);        // 4,718,592
    float* c2r   = (float*)(A + 28135424);        // 4,718,592
    hbf*   wr1t  = (hbf*)(A + 32854016);          // 9*64*256*2 = 294,912
    hbf*   wr2t  = (hbf*)(A + 33148928);          // 9*64*64*2  =  73,728  (ends 33,222,656)
    // ---- phase 2 layout (region A, reused) ----
    hbf*   xtp    = (hbf*)A;                      // 20,480,000
    float* c5acc  = (float*)(A + 20480000);       //  9,437,184  (fill xtp+c5acc = 29,917,184)
    hbf*   wt     = (hbf*)(A + 29917184);         // 18,874,368
    float* pooled = (float*)(A + 48791552);       //    819,200
    float* pconv  = (float*)(A + 49610752);       //    204,800
    float* M      = (float*)(A + 49815552);       //  1,843,200  (ends 51,658,752)
    // ---- phase 2b (after conv5), aliased over xtp ----
    hbf*   c5out = (hbf*)A;                       //  4,718,592
    float* c6s   = (float*)(A + 4718592);         //  1,087,488
    float* c6o   = (float*)(A + 5806080);         //  4,349,952  (ends 10,156,032 < 20,480,000)
    // total ws: 663,552 + 51,658,752 = 52,322,304 B (same as round 3)

    // ---- phase 1: attention branch ----
    k_fill0<<<dim3(22868), 256, 0, stream>>>((uint32_t*)A, 5854208);
    k_c1trans<<<dim3(288, 8, 2), dim3(32, 8), 0, stream>>>(c1, c1t);
    k_wtrans_small<256><<<dim3(64), 256, 0, stream>>>(w_r1, wr1t);
    k_wtrans_small<64><<<dim3(16), 256, 0, stream>>>(w_r2, wr2t);
    k_dconv_mfma<256><<<dim3(288, 3), 256, 0, stream>>>(wr1t, c1t, r1acc);
    k_ep_r1<<<dim3(72), 256, 0, stream>>>(r1acc, bn_r1, r1t);
    k_dconv_mfma<64><<<dim3(288, 3), 256, 0, stream>>>(wr2t, r1t, qacc);
    k_ep_q<<<dim3(4608), 256, 0, stream>>>(qacc, bn_r2, q);
    k_conv1x1_c2<<<dim3(16, 12, 8), dim3(48, 4), 0, stream>>>(c2, w_r3, c2acc);
    k_up96<<<dim3(2 * 64 * 9216 / 256), 256, 0, stream>>>(c2acc, c2r, 64, bn_r3);
    k_attention<<<dim3(2 * 9216 / 256), 256, 0, stream>>>(q, c2r, att);
    // ---- phase 2: psp branch ----
    k_pool<<<dim3(4096), 64, 0, stream>>>(xin, pooled);
    k_pconv<<<dim3(50, 2), 512, 0, stream>>>(pooled, w_p1, bn_p1, w_p2, bn_p2,
                                             w_p3, bn_p3, w_p4, bn_p4, pconv);
    k_computeM<<<dim3(9, 512, 2), 64, 0, stream>>>(w_c5, pconv, M);
    k_fill0<<<dim3(29216), 256, 0, stream>>>((uint32_t*)xtp, 7479296);
    k_xtrans<<<dim3(72, 64, 2), dim3(32, 8), 0, stream>>>(xin, xtp);
    k_wtrans<<<dim3(4096), 256, 0, stream>>>(w_c5, wt);
    k_conv5_mfma<<<dim3(4, 36, 3), 256, 0, stream>>>(wt, xtp, c5acc);
    k_bnrelu_psp<<<dim3(512, 2), 256, 0, stream>>>(c5acc, M, bn_c5, c5out);
    // classifier (conv6 commuted before upsample) + attention aggregation
    k_conv6s<<<dim3(59, 12, 2), dim3(48, 4), 0, stream>>>(c5out, w_c6, c6s);
    k_up96<<<dim3(2 * 59 * 9216 / 256), 256, 0, stream>>>(c6s, c6o, 59, nullptr);
    k_final<<<dim3(2 * 59 * 9216 / 256), 256, 0, stream>>>(att, c6o, b_c6, out);
}

// Round 5
// 876.502 us; speedup vs baseline: 5.7403x; 1.1488x over previous
//
#include <hip/hip_runtime.h>
#include <hip/hip_bf16.h>
#include <cstddef>
#include <cstdint>

typedef __hip_bfloat16 hbf;
typedef __bf16 bf16x8 __attribute__((ext_vector_type(8)));
typedef float f32x4 __attribute__((ext_vector_type(4)));

// bn: y = x*s + t, s = g*rsqrt(v+eps), t = b - m*s
__device__ __forceinline__ void bn_coef(const float* __restrict__ p, int C, int c,
                                        float& s, float& t) {
    float g = p[c];
    float b = p[C + c];
    float m = p[2 * C + c];
    float v = p[3 * C + c];
    s = g * rsqrtf(v + 1e-5f);
    t = b - m * s;
}

// ---------------- zero-fill (dwords) --------------------------------------------
__global__ void k_fill0(uint32_t* __restrict__ p, int n) {
    int i = blockIdx.x * blockDim.x + threadIdx.x;
    if (i < n) p[i] = 0u;
}

// ---------------- c1 fp32 [2,256,96,96] -> c1t bf16 [n][100*100][256], pad=2 ----
__global__ __launch_bounds__(256) void k_c1trans(const float* __restrict__ x,
                                                 hbf* __restrict__ c1t) {
    __shared__ float tbuf[32][33];
    const int p0 = blockIdx.x * 32, c0 = blockIdx.y * 32, n = blockIdx.z;
    const int tx = threadIdx.x, ty = threadIdx.y;
#pragma unroll
    for (int i = 0; i < 4; ++i) {
        int ci = c0 + ty * 4 + i;
        tbuf[ty * 4 + i][tx] = x[((size_t)(n * 256 + ci)) * 9216 + p0 + tx];
    }
    __syncthreads();
#pragma unroll
    for (int i = 0; i < 4; ++i) {
        int p = p0 + ty * 4 + i;
        int pp = (p / 96 + 2) * 100 + (p % 96) + 2;
        c1t[((size_t)(n * 10000 + pp)) * 256 + c0 + tx] = __float2bfloat16(tbuf[tx][ty * 4 + i]);
    }
}

// ---------------- small conv weights [64,CI,3,3] fp32 -> [tap][64][CI] bf16 -----
template <int CI>
__global__ __launch_bounds__(256) void k_wtrans_small(const float* __restrict__ w,
                                                      hbf* __restrict__ wt) {
    int idx = blockIdx.x * 256 + threadIdx.x;   // 64*CI
    int co = idx / CI, ci = idx % CI;
    const float* s = w + ((size_t)(co * CI + ci)) * 9;
#pragma unroll
    for (int tap = 0; tap < 9; ++tap)
        wt[((size_t)(tap * 64 + co)) * CI + ci] = __float2bfloat16(s[tap]);
}

// ---------------- dilated 3x3 conv (d=2) MFMA: 64co x 64px tile, split-K by tap row
template <int CI>
__global__ __launch_bounds__(256) void k_dconv_mfma(const hbf* __restrict__ wt,
                                                    const hbf* __restrict__ it,
                                                    float* __restrict__ accout) {
    __shared__ hbf As[2048];   // [64 m][32 k]
    __shared__ hbf Bs[2048];   // [64 n][32 k]
    const int tid = threadIdx.x;
    const int l = tid & 63, w = tid >> 6;
    const int P0 = blockIdx.x * 64;
    const int g  = blockIdx.y;
    const int r0 = tid >> 2;
    const int koff = (tid & 3) * 8;

    const int p_abs = P0 + r0;
    const int n_i = p_abs / 9216;
    const int pl = p_abs % 9216;
    const hbf* gB = it + ((size_t)(n_i * 10000 + (pl / 96 + 2) * 100 + (pl % 96) + 2)) * CI + koff;

    const int wn = w * 16;
    const int fragoff = (l & 15) * 32 + (l >> 4) * 8;
    f32x4 acc[4];
#pragma unroll
    for (int i = 0; i < 4; ++i) acc[i] = {0.f, 0.f, 0.f, 0.f};
    hbf* ldsA = As + w * 512;
    hbf* ldsB = Bs + w * 512;

    for (int t = 0; t < 3; ++t) {
        const int tap = g * 3 + t;
        const int dtap = (tap / 3 - 1) * 200 + (tap % 3 - 1) * 2;  // dilation-2 offsets
        const hbf* gA = wt + ((size_t)(tap * 64 + r0)) * CI + koff;
        const hbf* gBt = gB + (ptrdiff_t)dtap * CI;
        for (int k0 = 0; k0 < CI; k0 += 32) {
            __syncthreads();
            __builtin_amdgcn_global_load_lds(
                (const __attribute__((address_space(1))) void*)(gA + k0),
                (__attribute__((address_space(3))) void*)ldsA, 16, 0, 0);
            __builtin_amdgcn_global_load_lds(
                (const __attribute__((address_space(1))) void*)(gBt + k0),
                (__attribute__((address_space(3))) void*)ldsB, 16, 0, 0);
            __syncthreads();
            bf16x8 bfr = *(const bf16x8*)(Bs + wn * 32 + fragoff);
#pragma unroll
            for (int ti = 0; ti < 4; ++ti) {
                bf16x8 af = *(const bf16x8*)(As + ti * 512 + fragoff);
                acc[ti] = __builtin_amdgcn_mfma_f32_16x16x32_bf16(af, bfr, acc[ti], 0, 0, 0);
            }
        }
    }
    const int px = P0 + wn + (l & 15);
    const int n2 = px / 9216, pl2 = px % 9216;
#pragma unroll
    for (int ti = 0; ti < 4; ++ti) {
        const int mrow = ti * 16 + (l >> 4) * 4;
        float* dst = accout + ((size_t)(n2 * 64 + mrow)) * 9216 + pl2;
#pragma unroll
        for (int r = 0; r < 4; ++r)
            atomicAdd(dst + (size_t)r * 9216, acc[ti][r]);
    }
}

// ---------------- ep_r1: BN+ReLU(r1acc) -> r1t bf16 padded-transposed -----------
__global__ __launch_bounds__(256) void k_ep_r1(const float* __restrict__ acc,
                                               const float* __restrict__ bnp,
                                               hbf* __restrict__ r1t) {
    __shared__ float ss[64], st[64];
    if (threadIdx.x < 64) {
        float s, t; bn_coef(bnp, 64, threadIdx.x, s, t);
        ss[threadIdx.x] = s; st[threadIdx.x] = t;
    }
    __syncthreads();
    const int pi = blockIdx.x * 256 + threadIdx.x;
    const int n = pi / 9216, pl = pi % 9216;
    const int pp = (pl / 96 + 2) * 100 + (pl % 96) + 2;
    hbf* dst = r1t + ((size_t)(n * 10000 + pp)) * 64;
    const float* src = acc + (size_t)n * 64 * 9216 + pl;
#pragma unroll
    for (int co = 0; co < 64; ++co)
        dst[co] = __float2bfloat16(fmaxf(fmaf(src[(size_t)co * 9216], ss[co], st[co]), 0.f));
}

// ---------------- ep_q: elementwise BN+ReLU(qacc) -> q fp32 planar --------------
__global__ void k_ep_q(const float* __restrict__ acc, const float* __restrict__ bnp,
                       float* __restrict__ q) {
    int idx = blockIdx.x * blockDim.x + threadIdx.x;  // 2*64*9216
    int c = (idx / 9216) & 63;
    float s, t; bn_coef(bnp, 64, c, s, t);
    q[idx] = fmaxf(fmaf(acc[idx], s, t), 0.f);
}

// ---------------- 1x1 conv on c2 (512->64), ci split 4-ways, atomic -------------
__global__ __launch_bounds__(192) void k_conv1x1_c2(const float* __restrict__ c2,
                                                    const float* __restrict__ w,
                                                    float* __restrict__ outacc) {
    const int x = threadIdx.x;
    const int y = blockIdx.y * 4 + threadIdx.y;
    const int n = blockIdx.z >> 2;
    const int ci0 = (blockIdx.z & 3) * 128;
    const int cg = blockIdx.x;
    const int p = y * 48 + x;
    float acc[4];
#pragma unroll
    for (int j = 0; j < 4; ++j) acc[j] = 0.f;
    for (int ci = ci0; ci < ci0 + 128; ++ci) {
        float iv = c2[(size_t)(n * 512 + ci) * 2304 + p];
#pragma unroll
        for (int j = 0; j < 4; ++j)
            acc[j] = fmaf(iv, w[(size_t)(cg * 4 + j) * 512 + ci], acc[j]);
    }
#pragma unroll
    for (int j = 0; j < 4; ++j)
        atomicAdd(&outacc[(size_t)(n * 64 + cg * 4 + j) * 2304 + p], acc[j]);
}

// ---------------- bilinear 48->96 (align_corners), optional BN+ReLU -------------
__global__ void k_up96(const float* __restrict__ src, float* __restrict__ dst,
                       int C, const float* __restrict__ bnp) {
    int idx = blockIdx.x * blockDim.x + threadIdx.x;  // 2*C*9216
    int p = idx % 9216;
    int nc = idx / 9216;
    int c = nc % C;
    int y = p / 96, x = p % 96;
    int yn = y * 47, xn = x * 47;
    int y0 = yn / 95, x0 = xn / 95;
    float wy = (float)(yn - y0 * 95) * (1.f / 95.f);
    float wx = (float)(xn - x0 * 95) * (1.f / 95.f);
    int y1 = min(y0 + 1, 47), x1 = min(x0 + 1, 47);
    const float* sp = src + (size_t)nc * 2304;
    float v00 = sp[y0 * 48 + x0], v01 = sp[y0 * 48 + x1];
    float v10 = sp[y1 * 48 + x0], v11 = sp[y1 * 48 + x1];
    float v = (v00 * (1.f - wx) + v01 * wx) * (1.f - wy)
            + (v10 * (1.f - wx) + v11 * wx) * wy;
    if (bnp) {
        float s, t; bn_coef(bnp, C, c, s, t);
        v = fmaxf(fmaf(v, s, t), 0.f);
    }
    dst[idx] = v;
}

// ---------------- energy + softmax -> att [n,9216,9] ---------------------------
__global__ __launch_bounds__(256) void k_attention(const float* __restrict__ q,
                                                   const float* __restrict__ kf,
                                                   float* __restrict__ att) {
    int tid = blockIdx.x * 256 + threadIdx.x;  // 2*9216
    int n = tid / 9216, p = tid % 9216;
    int y = p / 96, x = p % 96;
    float qv[64];
    const float* qb = q + (size_t)n * 64 * 9216 + p;
#pragma unroll
    for (int c = 0; c < 64; ++c) qv[c] = qb[(size_t)c * 9216];
    float e[9];
    const float* kb = kf + (size_t)n * 64 * 9216;
#pragma unroll
    for (int ky = 0; ky < 3; ++ky)
#pragma unroll
        for (int kx = 0; kx < 3; ++kx) {
            int yy = y + 2 * ky - 2, xx = x + 2 * kx - 2;
            float s = 0.f;
            if (yy >= 0 && yy < 96 && xx >= 0 && xx < 96) {
                const float* kp = kb + yy * 96 + xx;
#pragma unroll
                for (int c = 0; c < 64; ++c) s = fmaf(qv[c], kp[(size_t)c * 9216], s);
            }
            e[ky * 3 + kx] = s;
        }
    float m = e[0];
#pragma unroll
    for (int k = 1; k < 9; ++k) m = fmaxf(m, e[k]);
    float sum = 0.f;
#pragma unroll
    for (int k = 0; k < 9; ++k) { e[k] = __expf(e[k] - m); sum += e[k]; }
    float inv = 1.f / sum;
    float* ap = att + (size_t)tid * 9;
#pragma unroll
    for (int k = 0; k < 9; ++k) ap[k] = e[k] * inv;
}

// ---------------- adaptive avg pools s=1,2,3,6 -> pooled [n,2048,50] ------------
__global__ __launch_bounds__(64) void k_pool(const float* __restrict__ xin,
                                             float* __restrict__ pooled) {
    int b = blockIdx.x;            // n*2048+c
    int t = threadIdx.x;
    __shared__ float cells[50];
    if (t < 50) cells[t] = 0.f;
    __syncthreads();
    float rs = 0.f;
    if (t < 48) {
        const float* row = xin + (size_t)b * 2304 + t * 48;
        float s6[6];
#pragma unroll
        for (int j = 0; j < 6; ++j) {
            float s = 0.f;
#pragma unroll
            for (int i = 0; i < 8; ++i) s += row[j * 8 + i];
            s6[j] = s;
        }
        float s3a = s6[0] + s6[1], s3b = s6[2] + s6[3], s3c = s6[4] + s6[5];
        float s2a = s3a + s6[2], s2b = s6[3] + s3c;
        rs = s2a + s2b;
        int r6 = t >> 3, r3 = t >> 4, r2 = t / 24;
        atomicAdd(&cells[14 + r6 * 6 + 0], s6[0]);
        atomicAdd(&cells[14 + r6 * 6 + 1], s6[1]);
        atomicAdd(&cells[14 + r6 * 6 + 2], s6[2]);
        atomicAdd(&cells[14 + r6 * 6 + 3], s6[3]);
        atomicAdd(&cells[14 + r6 * 6 + 4], s6[4]);
        atomicAdd(&cells[14 + r6 * 6 + 5], s6[5]);
        atomicAdd(&cells[5 + r3 * 3 + 0], s3a);
        atomicAdd(&cells[5 + r3 * 3 + 1], s3b);
        atomicAdd(&cells[5 + r3 * 3 + 2], s3c);
        atomicAdd(&cells[1 + r2 * 2 + 0], s2a);
        atomicAdd(&cells[1 + r2 * 2 + 1], s2b);
    }
#pragma unroll
    for (int off = 32; off > 0; off >>= 1) rs += __shfl_down(rs, off);
    if (t == 0) atomicAdd(&cells[0], rs);
    __syncthreads();
    if (t < 50) {
        float inv = (t == 0) ? (1.f / 2304.f)
                  : (t < 5)  ? (1.f / 576.f)
                  : (t < 14) ? (1.f / 256.f)
                             : (1.f / 64.f);
        pooled[(size_t)b * 50 + t] = cells[t] * inv;
    }
}

// ---------------- pconv2: 1x1 conv 2048->512 per cell + BN + ReLU ---------------
// grid(512, 2) block(64); lane = cell. pooled reads coalesced, weight broadcast.
__global__ __launch_bounds__(64) void k_pconv2(const float* __restrict__ pooled,
        const float* __restrict__ wp1, const float* __restrict__ bn1,
        const float* __restrict__ wp2, const float* __restrict__ bn2,
        const float* __restrict__ wp3, const float* __restrict__ bn3,
        const float* __restrict__ wp4, const float* __restrict__ bn4,
        float* __restrict__ pconv) {
    const int co = blockIdx.x, n = blockIdx.y;
    const int t = threadIdx.x;
    const int cell = (t < 50) ? t : 49;
    const float* w; const float* bnp;
    if (cell == 0)      { w = wp1; bnp = bn1; }
    else if (cell < 5)  { w = wp2; bnp = bn2; }
    else if (cell < 14) { w = wp3; bnp = bn3; }
    else                { w = wp4; bnp = bn4; }
    const float* pin = pooled + (size_t)n * 2048 * 50 + cell;
    const float* wr = w + (size_t)co * 2048;
    float a = 0.f;
#pragma unroll 4
    for (int c = 0; c < 2048; ++c)
        a = fmaf(pin[(size_t)c * 50], wr[c], a);
    float s, tt; bn_coef(bnp, 512, co, s, tt);
    if (t < 50)
        pconv[((size_t)n * 512 + co) * 50 + cell] = fmaxf(fmaf(a, s, tt), 0.f);
}

// ---------------- w5 fp32 [co][4096][9] psp slice -> wpsp bf16 [tap][b][c][co] --
// grid(8, 4, 8) block(256); reads lane-streamed, writes 128B-coalesced per wave.
__global__ __launch_bounds__(256) void k_wpsp_trans(const float* __restrict__ w5,
                                                    hbf* __restrict__ wpsp) {
    const int co = blockIdx.x * 64 + (threadIdx.x & 63);
    const int b = blockIdx.y;
    const int c0 = blockIdx.z * 64 + (threadIdx.x >> 6) * 16;
    for (int i = 0; i < 16; ++i) {
        int c = c0 + i;
        const float* s = w5 + ((size_t)co * 4096 + 2048 + b * 512 + c) * 9;
#pragma unroll
        for (int tap = 0; tap < 9; ++tap)
            wpsp[(((size_t)(tap * 4 + b) * 512) + c) * 512 + co] = __float2bfloat16(s[tap]);
    }
}

// ---------------- computeM2: M[n,co,tap,cell] via coalesced bf16 weights --------
// grid(8, 9, 14) block(64): z = n*7 + chunk; lane = co within group of 64.
__global__ __launch_bounds__(64) void k_computeM2(const hbf* __restrict__ wpsp,
                                                  const float* __restrict__ pconv,
                                                  float* __restrict__ M) {
    const int cog = blockIdx.x, tap = blockIdx.y;
    const int n = blockIdx.z / 7, chunk = blockIdx.z % 7;
    const int cell0_t[7] = {0, 1, 5, 14, 23, 32, 41};
    const int ncell_t[7] = {1, 4, 9, 9, 9, 9, 9};
    const int btab[7]    = {0, 1, 2, 3, 3, 3, 3};
    const int cell0 = cell0_t[chunk], nc = ncell_t[chunk], b = btab[chunk];
    const int co = cog * 64 + threadIdx.x;
    const hbf* wb = wpsp + ((size_t)(tap * 4 + b) * 512) * 512 + co;
    const float* pc = pconv + (size_t)n * 512 * 50 + cell0;
    float acc[9];
#pragma unroll
    for (int j = 0; j < 9; ++j) acc[j] = 0.f;
    for (int c = 0; c < 512; ++c) {
        float w = __bfloat162float(wb[(size_t)c * 512]);
#pragma unroll
        for (int j = 0; j < 9; ++j)          // cells 0..8 past cell0 always in-bounds
            acc[j] = fmaf(w, pc[c * 50 + j], acc[j]);
    }
    float* Mp = M + ((size_t)(n * 512 + co) * 9 + tap) * 50 + cell0;
    for (int j = 0; j < nc; ++j) Mp[j] = acc[j];
}

// bilinear cell coefficients for branch with grid s x s at pixel (yy,xx) in 48x48
struct B4 { int c0, c1, c2, c3; float w0, w1, w2, w3; };
__device__ __forceinline__ B4 cell_interp(int yy, int xx, int s, int base) {
    int sm1 = s - 1;
    int yn = yy * sm1, xn = xx * sm1;
    int y0 = yn / 47, x0 = xn / 47;
    float wy = (float)(yn - y0 * 47) * (1.f / 47.f);
    float wx = (float)(xn - x0 * 47) * (1.f / 47.f);
    int y1 = min(y0 + 1, sm1), x1 = min(x0 + 1, sm1);
    B4 r;
    r.c0 = base + y0 * s + x0; r.c1 = base + y0 * s + x1;
    r.c2 = base + y1 * s + x0; r.c3 = base + y1 * s + x1;
    r.w0 = (1.f - wy) * (1.f - wx); r.w1 = (1.f - wy) * wx;
    r.w2 = wy * (1.f - wx);         r.w3 = wy * wx;
    return r;
}

// ---------------- x (fp32 [n,2048,48,48]) -> xtp (bf16 [n,50*50,2048], pad=0) ---
__global__ __launch_bounds__(256) void k_xtrans(const float* __restrict__ x,
                                                hbf* __restrict__ xtp) {
    __shared__ float tbuf[32][33];
    const int p0 = blockIdx.x * 32, c0 = blockIdx.y * 32, n = blockIdx.z;
    const int tx = threadIdx.x, ty = threadIdx.y;
#pragma unroll
    for (int i = 0; i < 4; ++i) {
        int ci = c0 + ty * 4 + i;
        tbuf[ty * 4 + i][tx] = x[((size_t)(n * 2048 + ci)) * 2304 + p0 + tx];
    }
    __syncthreads();
#pragma unroll
    for (int i = 0; i < 4; ++i) {
        int p = p0 + ty * 4 + i;
        int pp = (p / 48 + 1) * 50 + (p % 48) + 1;
        xtp[((size_t)(n * 2500 + pp)) * 2048 + c0 + tx] = __float2bfloat16(tbuf[tx][ty * 4 + i]);
    }
}

// ---------------- w_c5 fp32 [co,4096,9] (ci<2048) -> wt bf16 [tap,co,ci] --------
__global__ __launch_bounds__(256) void k_wtrans(const float* __restrict__ w5,
                                                hbf* __restrict__ wt) {
    int idx = blockIdx.x * 256 + threadIdx.x;   // 512*2048
    int co = idx >> 11, ci = idx & 2047;
    const float* s = w5 + ((size_t)co * 4096 + ci) * 9;
#pragma unroll
    for (int tap = 0; tap < 9; ++tap)
        wt[((size_t)(tap * 512 + co)) * 2048 + ci] = __float2bfloat16(s[tap]);
}

// ---------------- conv5 direct part: MFMA implicit GEMM, split-K by tap group ---
__global__ __launch_bounds__(256) void k_conv5_mfma(const hbf* __restrict__ wt,
                                                    const hbf* __restrict__ xtp,
                                                    float* __restrict__ c5acc) {
    __shared__ hbf As[4096];   // [128 m][32 k]
    __shared__ hbf Bs[4096];   // [128 n][32 k]
    const int tid = threadIdx.x;
    const int l = tid & 63, w = tid >> 6;
    const int m0 = blockIdx.x * 128;
    const int P0 = blockIdx.y * 128;
    const int g  = blockIdx.z;
    const int n_img = P0 / 2304;
    const int pbase = P0 - n_img * 2304;
    const int r0 = tid >> 2;
    const int koff = (tid & 3) * 8;

    const int p_r0 = pbase + r0;
    const int p_r1 = p_r0 + 64;
    const size_t bB0 = ((size_t)(n_img * 2500 + p_r0 + 2 * (p_r0 / 48) + 51)) * 2048 + koff;
    const size_t bB1 = ((size_t)(n_img * 2500 + p_r1 + 2 * (p_r1 / 48) + 51)) * 2048 + koff;

    const int wm = (w & 1) * 64, wn = (w >> 1) * 64;
    const int fragoff = (l & 15) * 32 + (l >> 4) * 8;
    f32x4 acc[4][4];
#pragma unroll
    for (int i = 0; i < 4; ++i)
#pragma unroll
        for (int j = 0; j < 4; ++j) acc[i][j] = {0.f, 0.f, 0.f, 0.f};

    hbf* ldsA0 = As + w * 512;
    hbf* ldsA1 = As + 2048 + w * 512;
    hbf* ldsB0 = Bs + w * 512;
    hbf* ldsB1 = Bs + 2048 + w * 512;

    for (int t = 0; t < 3; ++t) {
        const int tap = g * 3 + t;
        const int dtap = (tap / 3 - 1) * 50 + (tap % 3 - 1);
        const hbf* gA0 = wt + ((size_t)(tap * 512 + m0 + r0)) * 2048 + koff;
        const hbf* gA1 = gA0 + (size_t)64 * 2048;
        const hbf* gB0 = xtp + bB0 + (ptrdiff_t)dtap * 2048;
        const hbf* gB1 = xtp + bB1 + (ptrdiff_t)dtap * 2048;
        for (int k0 = 0; k0 < 2048; k0 += 32) {
            __syncthreads();
            __builtin_amdgcn_global_load_lds(
                (const __attribute__((address_space(1))) void*)(gA0 + k0),
                (__attribute__((address_space(3))) void*)ldsA0, 16, 0, 0);
            __builtin_amdgcn_global_load_lds(
                (const __attribute__((address_space(1))) void*)(gA1 + k0),
                (__attribute__((address_space(3))) void*)ldsA1, 16, 0, 0);
            __builtin_amdgcn_global_load_lds(
                (const __attribute__((address_space(1))) void*)(gB0 + k0),
                (__attribute__((address_space(3))) void*)ldsB0, 16, 0, 0);
            __builtin_amdgcn_global_load_lds(
                (const __attribute__((address_space(1))) void*)(gB1 + k0),
                (__attribute__((address_space(3))) void*)ldsB1, 16, 0, 0);
            __syncthreads();
            bf16x8 af[4], bfr[4];
#pragma unroll
            for (int ti = 0; ti < 4; ++ti)
                af[ti] = *(const bf16x8*)(As + wm * 32 + ti * 512 + fragoff);
#pragma unroll
            for (int tj = 0; tj < 4; ++tj)
                bfr[tj] = *(const bf16x8*)(Bs + wn * 32 + tj * 512 + fragoff);
#pragma unroll
            for (int ti = 0; ti < 4; ++ti)
#pragma unroll
                for (int tj = 0; tj < 4; ++tj)
                    acc[ti][tj] = __builtin_amdgcn_mfma_f32_16x16x32_bf16(
                        af[ti], bfr[tj], acc[ti][tj], 0, 0, 0);
        }
    }
#pragma unroll
    for (int ti = 0; ti < 4; ++ti) {
        const int mrow = wm + ti * 16 + (l >> 4) * 4;
#pragma unroll
        for (int tj = 0; tj < 4; ++tj) {
            const int p = pbase + wn + tj * 16 + (l & 15);
            float* dst = c5acc + ((size_t)(n_img * 512 + m0 + mrow)) * 2304 + p;
#pragma unroll
            for (int r = 0; r < 4; ++r)
                atomicAdd(dst + (size_t)r * 2304, acc[ti][tj][r]);
        }
    }
}

// ---------------- epilogue: + psp(M)-part, BN, ReLU -> c5out bf16 ---------------
__global__ __launch_bounds__(256) void k_bnrelu_psp(const float* __restrict__ c5acc,
                                                    const float* __restrict__ M,
                                                    const float* __restrict__ bnp,
                                                    hbf* __restrict__ c5out) {
    const int co = blockIdx.x, n = blockIdx.y;
    __shared__ float Ms[450];
    const float* Mrow = M + ((size_t)(n * 512 + co)) * 450;
    for (int i = threadIdx.x; i < 450; i += 256) Ms[i] = Mrow[i];
    __syncthreads();
    float s, t; bn_coef(bnp, 512, co, s, t);
    const size_t base = ((size_t)(n * 512 + co)) * 2304;
#pragma unroll
    for (int i = 0; i < 9; ++i) {
        int p = threadIdx.x + i * 256;
        int y = p / 48, x = p % 48;
        float a = c5acc[base + p];
#pragma unroll
        for (int ky = 0; ky < 3; ++ky) {
            int yy = y + ky - 1;
            if (yy < 0 || yy > 47) continue;
#pragma unroll
            for (int kx = 0; kx < 3; ++kx) {
                int xx = x + kx - 1;
                if (xx < 0 || xx > 47) continue;
                const float* Mp = Ms + (ky * 3 + kx) * 50;
                float sa = Mp[0];
                B4 b2 = cell_interp(yy, xx, 2, 1);
                B4 b3 = cell_interp(yy, xx, 3, 5);
                B4 b6 = cell_interp(yy, xx, 6, 14);
                sa = fmaf(b2.w0, Mp[b2.c0], sa); sa = fmaf(b2.w1, Mp[b2.c1], sa);
                sa = fmaf(b2.w2, Mp[b2.c2], sa); sa = fmaf(b2.w3, Mp[b2.c3], sa);
                sa = fmaf(b3.w0, Mp[b3.c0], sa); sa = fmaf(b3.w1, Mp[b3.c1], sa);
                sa = fmaf(b3.w2, Mp[b3.c2], sa); sa = fmaf(b3.w3, Mp[b3.c3], sa);
                sa = fmaf(b6.w0, Mp[b6.c0], sa); sa = fmaf(b6.w1, Mp[b6.c1], sa);
                sa = fmaf(b6.w2, Mp[b6.c2], sa); sa = fmaf(b6.w3, Mp[b6.c3], sa);
                a += sa;
            }
        }
        c5out[base + p] = __float2bfloat16(fmaxf(fmaf(a, s, t), 0.f));
    }
}

// ---------------- conv6 at 48x48 (512->59, no bias), c5out bf16 -----------------
__global__ __launch_bounds__(192) void k_conv6s(const hbf* __restrict__ c5o,
                                                const float* __restrict__ w,
                                                float* __restrict__ out) {
    const int x = threadIdx.x;
    const int y = blockIdx.y * 4 + threadIdx.y;
    const int n = blockIdx.z;
    const int co = blockIdx.x;
    const int p = y * 48 + x;
    const hbf* ip = c5o + (size_t)n * 512 * 2304 + p;
    const float* wr = w + (size_t)co * 512;
    float a = 0.f;
    for (int ci = 0; ci < 512; ++ci)
        a = fmaf(__bfloat162float(ip[(size_t)ci * 2304]), wr[ci], a);
    out[((size_t)n * 59 + co) * 2304 + p] = a;
}

// ---------------- final: out = bias + sum_k att[k]*c6o[tap_k] -------------------
__global__ void k_final(const float* __restrict__ att, const float* __restrict__ c6o,
                        const float* __restrict__ bias, float* __restrict__ out) {
    int idx = blockIdx.x * blockDim.x + threadIdx.x;  // 2*59*9216
    int p = idx % 9216;
    int nc = idx / 9216;
    int cls = nc % 59, n = nc / 59;
    int y = p / 96, x = p % 96;
    const float* ar = att + ((size_t)n * 9216 + p) * 9;
    const float* cp = c6o + (size_t)nc * 9216;
    float a = bias[cls];
#pragma unroll
    for (int ky = 0; ky < 3; ++ky)
#pragma unroll
        for (int kx = 0; kx < 3; ++kx) {
            int yy = y + 2 * ky - 2, xx = x + 2 * kx - 2;
            if (yy >= 0 && yy < 96 && xx >= 0 && xx < 96)
                a = fmaf(ar[ky * 3 + kx], cp[yy * 96 + xx], a);
        }
    out[idx] = a;
}

extern "C" void kernel_launch(void* const* d_in, const int* in_sizes, int n_in,
                              void* d_out, int out_size, void* d_ws, size_t ws_size,
                              hipStream_t stream) {
    const float* c1    = (const float*)d_in[0];
    const float* c2    = (const float*)d_in[1];
    const float* xin   = (const float*)d_in[2];
    const float* w_r1  = (const float*)d_in[3];
    const float* bn_r1 = (const float*)d_in[4];
    const float* w_r2  = (const float*)d_in[5];
    const float* bn_r2 = (const float*)d_in[6];
    const float* w_r3  = (const float*)d_in[7];
    const float* bn_r3 = (const float*)d_in[8];
    const float* w_p1  = (const float*)d_in[9];
    const float* bn_p1 = (const float*)d_in[10];
    const float* w_p2  = (const float*)d_in[11];
    const float* bn_p2 = (const float*)d_in[12];
    const float* w_p3  = (const float*)d_in[13];
    const float* bn_p3 = (const float*)d_in[14];
    const float* w_p4  = (const float*)d_in[15];
    const float* bn_p4 = (const float*)d_in[16];
    const float* w_c5  = (const float*)d_in[17];
    const float* bn_c5 = (const float*)d_in[18];
    const float* w_c6  = (const float*)d_in[19];
    const float* b_c6  = (const float*)d_in[20];
    float* out = (float*)d_out;
    (void)in_sizes; (void)n_in; (void)out_size; (void)ws_size;

    char* base = (char*)d_ws;
    float* att = (float*)base;                    // 663,552 B
    char*  A   = base + 663552;
    // ---- phase 1 layout (region A) ----
    hbf*   c1t   = (hbf*)A;                       // 10,240,000
    hbf*   r1t   = (hbf*)(A + 10240000);          //  2,560,000
    float* r1acc = (float*)(A + 12800000);        //  4,718,592
    float* qacc  = (float*)(A + 17518592);        //  4,718,592
    float* c2acc = (float*)(A + 22237184);        //  1,179,648  (fill ends 23,416,832)
    float* q     = (float*)(A + 23416832);        //  4,718,592
    float* c2r   = (float*)(A + 28135424);        //  4,718,592
    hbf*   wr1t  = (hbf*)(A + 32854016);          //    294,912
    hbf*   wr2t  = (hbf*)(A + 33148928);          //     73,728  (ends 33,222,656)
    // ---- phase 2 early (region A): wpsp aliased under xtp, consumed pre-fill ----
    hbf*   wpsp   = (hbf*)A;                      // 18,874,368 (< xtp's 20,480,000)
    float* pooled = (float*)(A + 48791552);       //    819,200
    float* pconv  = (float*)(A + 49610752);       //    204,800
    float* M      = (float*)(A + 49815552);       //  1,843,200  (ends 51,658,752)
    // ---- phase 2 main (region A, reuses wpsp space) ----
    hbf*   xtp    = (hbf*)A;                      // 20,480,000
    float* c5acc  = (float*)(A + 20480000);       //  9,437,184
    hbf*   wt     = (hbf*)(A + 29917184);         // 18,874,368
    // ---- phase 2b (after conv5), aliased over xtp ----
    hbf*   c5out = (hbf*)A;                       //  4,718,592
    float* c6s   = (float*)(A + 4718592);         //  1,087,488
    float* c6o   = (float*)(A + 5806080);         //  4,349,952  (ends 10,156,032)
    // total ws: 663,552 + 51,658,752 = 52,322,304 B (unchanged)

    // ---- phase 1: attention branch ----
    k_fill0<<<dim3(22868), 256, 0, stream>>>((uint32_t*)A, 5854208);
    k_c1trans<<<dim3(288, 8, 2), dim3(32, 8), 0, stream>>>(c1, c1t);
    k_wtrans_small<256><<<dim3(64), 256, 0, stream>>>(w_r1, wr1t);
    k_wtrans_small<64><<<dim3(16), 256, 0, stream>>>(w_r2, wr2t);
    k_dconv_mfma<256><<<dim3(288, 3), 256, 0, stream>>>(wr1t, c1t, r1acc);
    k_ep_r1<<<dim3(72), 256, 0, stream>>>(r1acc, bn_r1, r1t);
    k_dconv_mfma<64><<<dim3(288, 3), 256, 0, stream>>>(wr2t, r1t, qacc);
    k_ep_q<<<dim3(4608), 256, 0, stream>>>(qacc, bn_r2, q);
    k_conv1x1_c2<<<dim3(16, 12, 8), dim3(48, 4), 0, stream>>>(c2, w_r3, c2acc);
    k_up96<<<dim3(2 * 64 * 9216 / 256), 256, 0, stream>>>(c2acc, c2r, 64, bn_r3);
    k_attention<<<dim3(2 * 9216 / 256), 256, 0, stream>>>(q, c2r, att);
    // ---- phase 2: psp branch ----
    k_pool<<<dim3(4096), 64, 0, stream>>>(xin, pooled);
    k_pconv2<<<dim3(512, 2), 64, 0, stream>>>(pooled, w_p1, bn_p1, w_p2, bn_p2,
                                              w_p3, bn_p3, w_p4, bn_p4, pconv);
    k_wpsp_trans<<<dim3(8, 4, 8), 256, 0, stream>>>(w_c5, wpsp);
    k_computeM2<<<dim3(8, 9, 14), 64, 0, stream>>>(wpsp, pconv, M);
    k_fill0<<<dim3(29216), 256, 0, stream>>>((uint32_t*)xtp, 7479296);
    k_xtrans<<<dim3(72, 64, 2), dim3(32, 8), 0, stream>>>(xin, xtp);
    k_wtrans<<<dim3(4096), 256, 0, stream>>>(w_c5, wt);
    k_conv5_mfma<<<dim3(4, 36, 3), 256, 0, stream>>>(wt, xtp, c5acc);
    k_bnrelu_psp<<<dim3(512, 2), 256, 0, stream>>>(c5acc, M, bn_c5, c5out);
    // classifier (conv6 commuted before upsample) + attention aggregation
    k_conv6s<<<dim3(59, 12, 2), dim3(48, 4), 0, stream>>>(c5out, w_c6, c6s);
    k_up96<<<dim3(2 * 59 * 9216 / 256), 256, 0, stream>>>(c6s, c6o, 59, nullptr);
    k_final<<<dim3(2 * 59 * 9216 / 256), 256, 0, stream>>>(att, c6o, b_c6, out);
}